// Round 6
// baseline (6483.194 us; speedup 1.0000x reference)
//
#include <hip/hip_runtime.h>
#include <hip/hip_cooperative_groups.h>

namespace cg = cooperative_groups;

typedef _Float16 f16;
typedef f16 f16x8 __attribute__((ext_vector_type(8)));
typedef float f32x4 __attribute__((ext_vector_type(4)));
typedef unsigned int u32x4 __attribute__((ext_vector_type(4)));

#define TSTEPS 128
#define NBLK 256
#define NTHR 768
// 3 shared h-tile buffers x 48 KB + dedicated stash 3 x 3840 B = 158,976 B
#define LDS_BYTES 158976
#define STASH_F16 73728            // f16 offset of stash region (= 147456 B)

// ---------------- workspace layout (bytes) ----------------
#define WT_BYTES (3ull*128*32*64*16)            // swizzled f16 weights: 12,582,912
#define H_OFF    (WT_BYTES)
#define H_BYTES  (3ull*2*768*512*2)             // h double buffers (f16): 4,718,592
#define S1_OFF   (H_OFF + H_BYTES)
#define O1_OFF   (S1_OFF + 1536*4)
#define Y1_OFF   (O1_OFF + 1536*4)
#define S2_OFF   (Y1_OFF + 256ull*1024*4)
#define O2_OFF   (S2_OFF + 1024*4)
#define Y2_OFF   (O2_OFF + 1024*4)
#define S3_OFF   (Y2_OFF + 256ull*102*4)
#define O3_OFF   (S3_OFF + 128*4)
#define BAR_OFF  (O3_OFF + 128*4)               // flag counters (zeroed in init)
#define WS_NEED  (BAR_OFF + 2048)

// R4: h buffers are WAVE-MAJOR swizzled: h[buf][cg8][m][c8], cg8=col/8 in
// [0,64), m in [0,768), c8 in [0,8). One wave's per-step output (48 rows x
// one cg8) is 768 B CONTIGUOUS -> coalesced store without any block barrier.
// f16 offset inside a buffer: (cg8*768 + m)*8 + c8.

struct Params {
  const int *t1, *t2, *t3;
  const float *emb, *lW, *lB;
  const float *g1, *be1, *W1, *b1;
  const float *g2, *be2, *W2, *b2;
  const float *g3, *be3, *W3, *b3;
  float* out;
  unsigned char* ws;
};

__device__ __forceinline__ float sigmf(float x) {
  x = fminf(fmaxf(x, -30.f), 30.f);
  return 1.f / (1.f + __expf(-x));
}
__device__ __forceinline__ float tanhf_(float x) {
  x = fminf(fmaxf(x, -15.f), 15.f);
  float e = __expf(-2.f * x);
  return (1.f - e) / (1.f + e);
}
__device__ __forceinline__ float wsum(float v) {
  #pragma unroll
  for (int m = 1; m < 64; m <<= 1) v += __shfl_xor(v, m, 64);
  return v;
}
__device__ __forceinline__ float vldh(const f16* p) {
  unsigned short u = *(volatile const unsigned short*)p;
  union { unsigned short s; f16 h; } cv; cv.s = u;
  return (float)cv.h;
}
__device__ __forceinline__ float vldf(const float* p) { return *(volatile const float*)p; }
__device__ __forceinline__ void  vstf(float* p, float v) { *(volatile float*)p = v; }
__device__ __forceinline__ f16x8 emb_frag(const float* e) {
  float4 fa = *(const float4*)e, fb = *(const float4*)(e + 4);
  f16x8 v;
  v[0]=(f16)fa.x; v[1]=(f16)fa.y; v[2]=(f16)fa.z; v[3]=(f16)fa.w;
  v[4]=(f16)fb.x; v[5]=(f16)fb.y; v[6]=(f16)fb.z; v[7]=(f16)fb.w;
  return v;
}

// Relaxed flag barrier (R5-proven): no acquire/release cache ops, L2 stays warm.
__device__ __forceinline__ void bar_arrive_wait(unsigned* ctr, unsigned target, int tid) {
  __syncthreads();
  if (tid == 0)
    __hip_atomic_fetch_add(ctr, 1u, __ATOMIC_RELAXED, __HIP_MEMORY_SCOPE_AGENT);
  if (tid < 64) {
    while (__hip_atomic_load(ctr, __ATOMIC_RELAXED, __HIP_MEMORY_SCOPE_AGENT) < target)
      __builtin_amdgcn_s_sleep(8);
  }
  __syncthreads();
}

#define MFMA16(a,b,c) __builtin_amdgcn_mfma_f32_16x16x32_f16((a),(b),(c),0,0,0)

// 256 blocks x 768 threads, 1 block/CU (proven cooperative shape).
// R6: __launch_bounds__ min-occupancy arg relaxed 3 -> 1. Occupancy is
// LDS-BOUND to 1 block/CU (158,976 B) regardless, but the "3" was capping
// arch-VGPRs at ~84 and forced the R5 weight hoist to SCRATCH (FETCH +95%,
// WRITE +62 MB, VGPR 84). min=1 frees the allocator to keep pb0/pb1 (64
// VGPRs) truly register-resident -> clean test of the weight-stream theory.
__global__ __launch_bounds__(NTHR, 1) void conv_lstm(Params P) {
  cg::grid_group grid = cg::this_grid();
  const int bid = blockIdx.x, tid = threadIdx.x;

  extern __shared__ __align__(16) f16 smem[];   // H0|H1|H2 (48 KB each) | stash

  f16*      WT   = (f16*)(P.ws);
  f16*      Hb   = (f16*)(P.ws + H_OFF);
  unsigned* bar  = (unsigned*)(P.ws + BAR_OFF); // [rg*16] 16 rg-ctrs, [256] grid ctr
  unsigned* gctr = bar + 256;

  // ---- init: weight swizzle into MFMA B-fragment order + zero h + zero ctrs ----
  {
    const int gt = bid * NTHR + tid;
    for (int slot = gt; slot < 786432; slot += NBLK * NTHR) {
      int lane = slot & 63, kkg = (slot >> 6) & 31, g16 = (slot >> 11) & 127, l = slot >> 18;
      int k = kkg * 32 + (lane >> 4) * 8;
      int p = g16 * 16 + (lane & 15);             // permuted gate-col: p = 4u+g
      int n = (p & 3) * 512 + (p >> 2);           // original col: g*512+u
      const float* s = P.lW + ((size_t)l * 1024 + k) * 2048 + n;
      f16x8 v;
      #pragma unroll
      for (int j = 0; j < 8; j++) v[j] = (f16)s[(size_t)j * 2048];
      *(f16x8*)(WT + (size_t)slot * 8) = v;
    }
    uint4 z4; z4.x = z4.y = z4.z = z4.w = 0u;
    uint4* zp = (uint4*)(P.ws + H_OFF);
    for (int i = gt; i < 294912; i += NBLK * NTHR) zp[i] = z4;
    if (bid == 0 && tid < 512) bar[tid] = 0u;
  }
  grid.sync();   // the ONE fence-ful sync: publishes WT / h-zeros / ctr-zeros

  // ---- thread geometry: 16 rowgroups x 16 colgroups ----
  const int sb   = tid >> 8;                      // layer sub-group (256 thr = 4 waves)
  const int tid2 = tid & 255;
  const int w2   = tid2 >> 6;                     // wave-in-subgroup: 32-pcol slice
  const int wv   = tid >> 6;                      // global wave id [0,12)
  const int L    = tid & 63;
  const int r16  = L & 15, quad = L >> 4;
  const int s4   = L & 3, r16q = r16 >> 2;
  const int rg   = bid >> 4, cgi = bid & 15;
  const int row0 = rg * 48;
  unsigned* rgc  = bar + rg * 16;

  const int ug = cgi * 32 + w2 * 8 + r16q;        // unit base for this lane
  float bia[2][4];
  #pragma unroll
  for (int ct2 = 0; ct2 < 2; ++ct2)
    #pragma unroll
    for (int g = 0; g < 4; ++g)
      bia[ct2][g] = P.lB[sb * 2048 + g * 512 + ug + ct2 * 4];
  float c6[6] = {0.f, 0.f, 0.f, 0.f, 0.f, 0.f};   // persistent c-state (VGPR)

  const size_t lstride = 768 * 512;
  const f16x8* Bb = (const f16x8*)WT
      + ((size_t)(sb * 128 + cgi * 8 + w2 * 2) * 32) * 64 + L;
  // stash in DEDICATED LDS (R2): [48][40] f16 per subgroup. Wave (sb,w2) owns
  // cols w2*8..w2*8+7 -> each row-chunk is exactly one 16B store.
  f16* stash = smem + STASH_F16 + sb * 1920;

  // R5/R6: PERMANENT register residency of the x-side kk=0..7 B-fragments
  // (16 x f16x8 = 64 VGPR). Weights are loop-invariant; holding them cuts
  // per-step L2 weight traffic 768 -> 576 KB/CU (-25%).
  f16x8 pb0[8], pb1[8];
  #pragma unroll
  for (int i = 0; i < 8; ++i) { pb0[i] = Bb[i * 64]; pb1[i] = Bb[i * 64 + 2048]; }

  // ---- wavefront: 3 layers in parallel; h-tiles staged ONCE into shared LDS ----
  for (int s = 0; s < TSTEPS + 2; ++s) {
    const int t = s - sb;
    const bool act = (t >= 0 && t < TSTEPS);
    f16* hdo = Hb + (size_t)(sb * 2 + (t & 1)) * lstride;

    // shared h-tile sources (slot arithmetic: (x)&1 is well-defined for x<0)
    const f16* hs0 = Hb + (size_t)(0 * 2 + ((s - 1) & 1)) * lstride;  // h_l0[s-1]
    const f16* hs1 = Hb + (size_t)(1 * 2 + ((s - 2) & 1)) * lstride;  // h_l1[s-2]
    const f16* hs2 = Hb + (size_t)(2 * 2 + ((s - 3) & 1)) * lstride;  // h_l2[s-3]

    // ---- stage: all 12 waves fill H0|H1|H2 (48 frag-blocks of 1 KB each) ----
    // R4: swizzled source -> lanes 0..15 read 256 B contiguous per (kk,quad).
    // (entering here, the previous step's rg-barrier guarantees LDS is free)
    #pragma unroll
    for (int i = 0; i < 12; ++i) {
      int fb = wv * 12 + i;                       // [0,144)
      int buf = fb / 48, inner = fb - buf * 48;
      int kk = inner / 3, rt = inner - kk * 3;
      const f16* src = (buf == 0) ? hs0 : ((buf == 1) ? hs1 : hs2);
      int m = row0 + rt * 16 + r16;
      int cg8 = kk * 4 + quad;
      u32x4 v = *(volatile const u32x4*)(src + ((size_t)cg8 * 768 + m) * 8);
      *(u32x4*)(smem + buf * 24576 + inner * 512 + L * 8) = v;
    }
    __syncthreads();                              // S1: stage -> MFMA reads

    f32x4 acc[3][2];
    #pragma unroll
    for (int a = 0; a < 3; a++)
      #pragma unroll
      for (int b = 0; b < 2; b++) acc[a][b] = (f32x4){0.f, 0.f, 0.f, 0.f};

    if (act) {
      // token/emb base pointers for layer 0 (per-lane row)
      const float *e0, *e1, *e2;
      if (sb == 0) {
        int m0 = row0 + r16, m1 = m0 + 16, m2 = m0 + 32;
        int b0 = m0 & 255, tx0 = m0 >> 8;
        int b1 = m1 & 255, tx1 = m1 >> 8;
        int b2 = m2 & 255, tx2 = m2 >> 8;
        const int* tp0 = (tx0 == 0) ? P.t1 : ((tx0 == 1) ? P.t2 : P.t3);
        const int* tp1 = (tx1 == 0) ? P.t1 : ((tx1 == 1) ? P.t2 : P.t3);
        const int* tp2 = (tx2 == 0) ? P.t1 : ((tx2 == 1) ? P.t2 : P.t3);
        e0 = P.emb + (size_t)tp0[b0 * TSTEPS + t] * 512;
        e1 = P.emb + (size_t)tp1[b1 * TSTEPS + t] * 512;
        e2 = P.emb + (size_t)tp2[b2 * TSTEPS + t] * 512;
      }
      const f16* xbuf = smem + (sb - 1) * 24576;  // valid for sb>0
      const f16* hbuf = smem + sb * 24576;

      // x-side kk 0..7: register-resident B (R5). FULL unroll -> static pb idx.
      #pragma unroll
      for (int kk = 0; kk < 8; ++kk) {
        f16x8 a0, a1, a2;
        if (sb == 0) {
          int k = kk * 32 + quad * 8;
          a0 = emb_frag(e0 + k); a1 = emb_frag(e1 + k); a2 = emb_frag(e2 + k);
        } else {
          a0 = *(const f16x8*)(xbuf + (kk * 3 + 0) * 512 + L * 8);
          a1 = *(const f16x8*)(xbuf + (kk * 3 + 1) * 512 + L * 8);
          a2 = *(const f16x8*)(xbuf + (kk * 3 + 2) * 512 + L * 8);
        }
        acc[0][0] = MFMA16(a0, pb0[kk], acc[0][0]);
        acc[1][0] = MFMA16(a1, pb0[kk], acc[1][0]);
        acc[2][0] = MFMA16(a2, pb0[kk], acc[2][0]);
        acc[0][1] = MFMA16(a0, pb1[kk], acc[0][1]);
        acc[1][1] = MFMA16(a1, pb1[kk], acc[1][1]);
        acc[2][1] = MFMA16(a2, pb1[kk], acc[2][1]);
      }
      // x-side kk 8..15: streamed B from L2 (as before)
      #pragma unroll 4
      for (int kk = 8; kk < 16; ++kk) {
        f16x8 a0, a1, a2;
        if (sb == 0) {
          int k = kk * 32 + quad * 8;
          a0 = emb_frag(e0 + k); a1 = emb_frag(e1 + k); a2 = emb_frag(e2 + k);
        } else {
          a0 = *(const f16x8*)(xbuf + (kk * 3 + 0) * 512 + L * 8);
          a1 = *(const f16x8*)(xbuf + (kk * 3 + 1) * 512 + L * 8);
          a2 = *(const f16x8*)(xbuf + (kk * 3 + 2) * 512 + L * 8);
        }
        f16x8 b0 = Bb[kk * 64], b1 = Bb[kk * 64 + 2048];
        acc[0][0] = MFMA16(a0, b0, acc[0][0]);
        acc[1][0] = MFMA16(a1, b0, acc[1][0]);
        acc[2][0] = MFMA16(a2, b0, acc[2][0]);
        acc[0][1] = MFMA16(a0, b1, acc[0][1]);
        acc[1][1] = MFMA16(a1, b1, acc[1][1]);
        acc[2][1] = MFMA16(a2, b1, acc[2][1]);
      }
      // h-side: k in [512,1024)
      #pragma unroll 4
      for (int kk = 16; kk < 32; ++kk) {
        int in3 = (kk - 16) * 3;
        f16x8 a0 = *(const f16x8*)(hbuf + (in3 + 0) * 512 + L * 8);
        f16x8 a1 = *(const f16x8*)(hbuf + (in3 + 1) * 512 + L * 8);
        f16x8 a2 = *(const f16x8*)(hbuf + (in3 + 2) * 512 + L * 8);
        f16x8 b0 = Bb[kk * 64], b1 = Bb[kk * 64 + 2048];
        acc[0][0] = MFMA16(a0, b0, acc[0][0]);
        acc[1][0] = MFMA16(a1, b0, acc[1][0]);
        acc[2][0] = MFMA16(a2, b0, acc[2][0]);
        acc[0][1] = MFMA16(a0, b1, acc[0][1]);
        acc[1][1] = MFMA16(a1, b1, acc[1][1]);
        acc[2][1] = MFMA16(a2, b1, acc[2][1]);
      }
    }
    // R2: no MFMA->elem sync (S2 removed; stash is dedicated LDS).

    // ---- elementwise: 4x4 lane<->reg transpose -> c/h; h out WAVE-LOCALLY ----
    // R3: S3 removed (wave-local handoff, lgkmcnt(0) only).
    // R4: store goes to the swizzled h layout -> lanes 0..47 write one 768 B
    // contiguous burst (fixes the R3 16B-partial-line write amplification).
    if (act) {
      #pragma unroll
      for (int rt = 0; rt < 3; ++rt) {
        #pragma unroll
        for (int ct2 = 0; ct2 < 2; ++ct2) {
          float x0 = acc[rt][ct2][0], x1 = acc[rt][ct2][1];
          float x2 = acc[rt][ct2][2], x3 = acc[rt][ct2][3];
          float a, b;
          a = (s4 & 1) ? x0 : x1;  b = (s4 & 1) ? x2 : x3;
          a = __shfl_xor(a, 1, 64); b = __shfl_xor(b, 1, 64);
          if (s4 & 1) { x0 = a; x2 = b; } else { x1 = a; x3 = b; }
          a = (s4 & 2) ? x0 : x2;  b = (s4 & 2) ? x1 : x3;
          a = __shfl_xor(a, 2, 64); b = __shfl_xor(b, 2, 64);
          if (s4 & 2) { x0 = a; x1 = b; } else { x2 = a; x3 = b; }
          float vi = x0 + bia[ct2][0], vj = x1 + bia[ct2][1];
          float vf = x2 + bia[ct2][2], vo = x3 + bia[ct2][3];
          int j = rt * 2 + ct2;
          float cn = sigmf(vf) * c6[j] + sigmf(vi) * tanhf_(vj);
          c6[j] = cn;
          int rl = rt * 16 + quad * 4 + s4;       // [0,48)
          int cl = w2 * 8 + ct2 * 4 + r16q;       // [0,32)
          stash[rl * 40 + cl] = (f16)(sigmf(vo) * tanhf_(cn));
        }
      }
      asm volatile("s_waitcnt lgkmcnt(0)" ::: "memory");  // wave-local LDS RAW fence
      if (L < 48) {                               // own 48x8-col block: 768 B burst
        u32x4 v = *(const u32x4*)(stash + L * 40 + w2 * 8);
        *(volatile u32x4*)(hdo + ((size_t)(cgi * 4 + w2) * 768 + row0 + L) * 8) = v;
      }
    }
    bar_arrive_wait(rgc, 16u * (unsigned)(s + 1), tid);  // per-rg (16 blocks), relaxed
  }

  // ---------------- epilogue: relaxed grid barriers + volatile buffers ----------------
  float* scale1 = (float*)(P.ws + S1_OFF); float* off1 = (float*)(P.ws + O1_OFF);
  float* y1    = (float*)(P.ws + Y1_OFF);
  float* scale2 = (float*)(P.ws + S2_OFF); float* off2 = (float*)(P.ws + O2_OFF);
  float* y2    = (float*)(P.ws + Y2_OFF);
  float* scale3 = (float*)(P.ws + S3_OFF); float* off3 = (float*)(P.ws + O3_OFF);
  const f16* h2f = Hb + (size_t)(2 * 2 + 1) * lstride;   // top layer, t=127 (slot 1)

  bar_arrive_wait(gctr, 256u, tid);               // all rgs done -> h2f complete

  const int wvg = bid * 12 + wv;
  const int Le  = tid & 63;
  const float SC = 1.0507009873554805f, AL = 1.6732632423543772f;

  // E1: BN1 -> fused scale/offset for 1536 cols (one wave per col)
  // R4: swizzled h2f read -> 64 lanes span 1 KB contiguous (was 64 lines).
  if (wvg < 1536) {
    int c = wvg, tx = c >> 9, u = c & 511;
    const f16* base = h2f + (size_t)(u >> 3) * 6144 + (size_t)tx * 2048 + (u & 7);
    float sm = 0.f, s2 = 0.f;
    for (int r = Le; r < 256; r += 64) {
      float v = vldh(base + (size_t)r * 8);
      sm += v; s2 += v * v;
    }
    sm = wsum(sm); s2 = wsum(s2);
    if (Le == 0) {
      float mu = sm * (1.f / 256.f);
      float var = s2 * (1.f / 256.f) - mu * mu;
      float sc = rsqrtf(var + 1e-3f) * P.g1[c];
      vstf(scale1 + c, sc); vstf(off1 + c, P.be1[c] - mu * sc);
    }
  }
  bar_arrive_wait(gctr, 512u, tid);

  // E2: y1 = selu(rep_n @ W1 + b1): block = 16-row slab x 64-col slice, slab in LDS
  {
    const int rb16 = (bid >> 4) * 16, cb = bid & 15;
    f16*   slab = smem;                           // [16][1536] f16 (49,152 B)
    float* scl  = (float*)(smem + 24576);         // [1536]
    float* ofl  = scl + 1536;                     // [1536]
    for (int e = tid; e < 3072; e += NTHR) {      // 16-B chunks of the slab
      int r = e / 192, seg = e % 192;
      int u8 = seg * 8, tx = u8 >> 9, u = u8 & 511;
      u32x4 v = *(volatile const u32x4*)(h2f + ((size_t)(u >> 3) * 768 + tx * 256 + rb16 + r) * 8);
      *(u32x4*)(slab + r * 1536 + seg * 8) = v;
    }
    for (int k2 = tid; k2 < 1536; k2 += NTHR) { scl[k2] = vldf(scale1 + k2); ofl[k2] = vldf(off1 + k2); }
    __syncthreads();
    int rgrp = tid >> 6;
    if (rgrp < 8) {
      int c = cb * 64 + (tid & 63);
      int r0 = rgrp * 2, r1 = r0 + 1;
      float a0 = 0.f, a1 = 0.f;
      for (int k = 0; k < 1536; ++k) {
        float w = P.W1[(size_t)k * 1024 + c];
        float sck = scl[k], ofk = ofl[k];
        a0 += ((float)slab[r0 * 1536 + k] * sck + ofk) * w;
        a1 += ((float)slab[r1 * 1536 + k] * sck + ofk) * w;
      }
      float x0 = a0 + P.b1[c], x1 = a1 + P.b1[c];
      vstf(y1 + (size_t)(rb16 + r0) * 1024 + c, SC * (x0 > 0.f ? x0 : AL * expm1f(x0)));
      vstf(y1 + (size_t)(rb16 + r1) * 1024 + c, SC * (x1 > 0.f ? x1 : AL * expm1f(x1)));
    }
  }
  bar_arrive_wait(gctr, 768u, tid);

  // E3: BN2 scale/offset for 1024 cols (one wave per col)
  if (wvg < 1024) {
    int c = wvg;
    float sm = 0.f, s2 = 0.f;
    for (int r = Le; r < 256; r += 64) {
      float v = vldf(y1 + (size_t)r * 1024 + c);
      sm += v; s2 += v * v;
    }
    sm = wsum(sm); s2 = wsum(s2);
    if (Le == 0) {
      float mu = sm * (1.f / 256.f);
      float var = s2 * (1.f / 256.f) - mu * mu;
      float sc = rsqrtf(var + 1e-3f) * P.g2[c];
      vstf(scale2 + c, sc); vstf(off2 + c, P.be2[c] - mu * sc);
    }
  }
  bar_arrive_wait(gctr, 1024u, tid);

  // E4: y2 = selu(y1n @ W2 + b2): one wave per batch row. (R1 rewrite, kept:
  // scale2/off2 staged to LDS once; y1 row staged via 4 wide volatile loads;
  // dot runs on LDS broadcasts instead of 3 serial volatile loads per k.)
  {
    float* sc2  = (float*)smem;                   // [1024]
    float* of2  = sc2 + 1024;                     // [1024]
    float* rowb = of2 + 1024;                     // [12][1024]
    for (int k = tid; k < 1024; k += NTHR) { sc2[k] = vldf(scale2 + k); of2[k] = vldf(off2 + k); }
    __syncthreads();
    if (wvg < 256) {
      const float* yr = y1 + (size_t)wvg * 1024;
      u32x4 r0 = *(volatile const u32x4*)(yr + Le * 16);
      u32x4 r1 = *(volatile const u32x4*)(yr + Le * 16 + 4);
      u32x4 r2 = *(volatile const u32x4*)(yr + Le * 16 + 8);
      u32x4 r3 = *(volatile const u32x4*)(yr + Le * 16 + 12);
      float* rw = rowb + wv * 1024 + Le * 16;
      *(u32x4*)(rw) = r0; *(u32x4*)(rw + 4) = r1;
      *(u32x4*)(rw + 8) = r2; *(u32x4*)(rw + 12) = r3;
      asm volatile("s_waitcnt lgkmcnt(0)" ::: "memory");  // wave-local LDS RAW fence
      const float* rb = rowb + wv * 1024;
      int c0 = Le, c1 = Le + 64;
      float a0 = 0.f, a1 = 0.f;
      #pragma unroll 4
      for (int k = 0; k < 1024; ++k) {
        float v = rb[k] * sc2[k] + of2[k];
        a0 += v * P.W2[(size_t)k * 102 + c0];
        if (c1 < 102) a1 += v * P.W2[(size_t)k * 102 + c1];
      }
      {
        float x = a0 + P.b2[c0];
        vstf(y2 + (size_t)wvg * 102 + c0, SC * (x > 0.f ? x : AL * expm1f(x)));
      }
      if (c1 < 102) {
        float x = a1 + P.b2[c1];
        vstf(y2 + (size_t)wvg * 102 + c1, SC * (x > 0.f ? x : AL * expm1f(x)));
      }
    }
  }
  bar_arrive_wait(gctr, 1280u, tid);

  // E5: BN3 scale/offset for 102 cols (one wave per col)
  if (wvg < 102) {
    int c = wvg;
    float sm = 0.f, s2 = 0.f;
    for (int r = Le; r < 256; r += 64) {
      float v = vldf(y2 + (size_t)r * 102 + c);
      sm += v; s2 += v * v;
    }
    sm = wsum(sm); s2 = wsum(s2);
    if (Le == 0) {
      float mu = sm * (1.f / 256.f);
      float var = s2 * (1.f / 256.f) - mu * mu;
      float sc = rsqrtf(var + 1e-3f) * P.g3[c];
      vstf(scale3 + c, sc); vstf(off3 + c, P.be3[c] - mu * sc);
    }
  }
  bar_arrive_wait(gctr, 1536u, tid);

  // E6: out = y2n @ W3 + b3: one wave per batch row
  if (wvg < 256) {
    int row = wvg;
    int c = Le & 3, kq = Le >> 2;
    float part = 0.f;
    for (int k = kq; k < 102; k += 16) {
      float v = vldf(y2 + (size_t)row * 102 + k) * vldf(scale3 + k) + vldf(off3 + k);
      part += v * P.W3[k * 4 + c];
    }
    #pragma unroll
    for (int m = 4; m < 64; m <<= 1) part += __shfl_xor(part, m, 64);
    if (Le < 4) P.out[row * 4 + Le] = part + P.b3[Le];
  }
}

extern "C" void kernel_launch(void* const* d_in, const int* in_sizes, int n_in,
                              void* d_out, int out_size, void* d_ws, size_t ws_size,
                              hipStream_t stream) {
  if (ws_size < (size_t)WS_NEED) return;
  (void)hipFuncSetAttribute((const void*)conv_lstm,
                            hipFuncAttributeMaxDynamicSharedMemorySize, LDS_BYTES);
  Params prm;
  prm.t1  = (const int*)d_in[0];
  prm.t2  = (const int*)d_in[1];
  prm.t3  = (const int*)d_in[2];
  prm.emb = (const float*)d_in[3];
  prm.lW  = (const float*)d_in[4];
  prm.lB  = (const float*)d_in[5];
  prm.g1  = (const float*)d_in[6];  prm.be1 = (const float*)d_in[7];
  prm.W1  = (const float*)d_in[8];  prm.b1  = (const float*)d_in[9];
  prm.g2  = (const float*)d_in[10]; prm.be2 = (const float*)d_in[11];
  prm.W2  = (const float*)d_in[12]; prm.b2  = (const float*)d_in[13];
  prm.g3  = (const float*)d_in[14]; prm.be3 = (const float*)d_in[15];
  prm.W3  = (const float*)d_in[16]; prm.b3  = (const float*)d_in[17];
  prm.out = (float*)d_out;
  prm.ws  = (unsigned char*)d_ws;
  void* args[] = { &prm };
  hipLaunchCooperativeKernel((void*)conv_lstm, dim3(NBLK), dim3(NTHR), args,
                             LDS_BYTES, stream);
}

// Round 7
// 4679.432 us; speedup vs baseline: 1.3855x; 1.3855x over previous
//
#include <hip/hip_runtime.h>
#include <hip/hip_cooperative_groups.h>

namespace cg = cooperative_groups;

typedef _Float16 f16;
typedef f16 f16x8 __attribute__((ext_vector_type(8)));
typedef float f32x4 __attribute__((ext_vector_type(4)));
typedef unsigned int u32x4 __attribute__((ext_vector_type(4)));

#define TSTEPS 128
#define NBLK 256
#define NTHR 768
// 3 shared h-tile buffers x 48 KB + dedicated stash 3 x 3840 B = 158,976 B
#define LDS_BYTES 158976
#define STASH_F16 73728            // f16 offset of stash region (= 147456 B)

// ---------------- workspace layout (bytes) ----------------
#define WT_BYTES (3ull*128*32*64*16)            // swizzled f16 weights: 12,582,912
#define H_OFF    (WT_BYTES)
#define H_BYTES  (3ull*2*768*512*2)             // h double buffers (f16): 4,718,592
#define S1_OFF   (H_OFF + H_BYTES)
#define O1_OFF   (S1_OFF + 1536*4)
#define Y1_OFF   (O1_OFF + 1536*4)
#define S2_OFF   (Y1_OFF + 256ull*1024*4)
#define O2_OFF   (S2_OFF + 1024*4)
#define Y2_OFF   (O2_OFF + 1024*4)
#define S3_OFF   (Y2_OFF + 256ull*102*4)
#define O3_OFF   (S3_OFF + 128*4)
#define BAR_OFF  (O3_OFF + 128*4)               // flag counters (zeroed in init)
#define WS_NEED  (BAR_OFF + 2048)

// R4: h buffers are WAVE-MAJOR swizzled: h[buf][cg8][m][c8], cg8=col/8 in
// [0,64), m in [0,768), c8 in [0,8). One wave's per-step output (48 rows x
// one cg8) is 768 B CONTIGUOUS -> coalesced store without any block barrier.
// f16 offset inside a buffer: (cg8*768 + m)*8 + c8.
// R7: weight-hoist (R5/R6) REVERTED -- allocator spills it to scratch
// regardless of __launch_bounds__ (FETCH +95%, dur +40%, two-round proof).

struct Params {
  const int *t1, *t2, *t3;
  const float *emb, *lW, *lB;
  const float *g1, *be1, *W1, *b1;
  const float *g2, *be2, *W2, *b2;
  const float *g3, *be3, *W3, *b3;
  float* out;
  unsigned char* ws;
};

__device__ __forceinline__ float sigmf(float x) {
  x = fminf(fmaxf(x, -30.f), 30.f);
  return 1.f / (1.f + __expf(-x));
}
__device__ __forceinline__ float tanhf_(float x) {
  x = fminf(fmaxf(x, -15.f), 15.f);
  float e = __expf(-2.f * x);
  return (1.f - e) / (1.f + e);
}
__device__ __forceinline__ float wsum(float v) {
  #pragma unroll
  for (int m = 1; m < 64; m <<= 1) v += __shfl_xor(v, m, 64);
  return v;
}
__device__ __forceinline__ float vldh(const f16* p) {
  unsigned short u = *(volatile const unsigned short*)p;
  union { unsigned short s; f16 h; } cv; cv.s = u;
  return (float)cv.h;
}
__device__ __forceinline__ float vldf(const float* p) { return *(volatile const float*)p; }
__device__ __forceinline__ void  vstf(float* p, float v) { *(volatile float*)p = v; }
__device__ __forceinline__ f16x8 emb_frag(const float* e) {
  float4 fa = *(const float4*)e, fb = *(const float4*)(e + 4);
  f16x8 v;
  v[0]=(f16)fa.x; v[1]=(f16)fa.y; v[2]=(f16)fa.z; v[3]=(f16)fa.w;
  v[4]=(f16)fb.x; v[5]=(f16)fb.y; v[6]=(f16)fb.z; v[7]=(f16)fb.w;
  return v;
}

// Conservative flag barrier (epilogue only): leading+trailing __syncthreads.
__device__ __forceinline__ void bar_arrive_wait(unsigned* ctr, unsigned target, int tid) {
  __syncthreads();
  if (tid == 0)
    __hip_atomic_fetch_add(ctr, 1u, __ATOMIC_RELAXED, __HIP_MEMORY_SCOPE_AGENT);
  if (tid < 64) {
    while (__hip_atomic_load(ctr, __ATOMIC_RELAXED, __HIP_MEMORY_SCOPE_AGENT) < target)
      __builtin_amdgcn_s_sleep(8);
  }
  __syncthreads();
}

// R7 hot-loop rg-barrier: NO trailing __syncthreads. All 12 waves poll the
// counter independently and proceed straight into staging on release.
// Safety: the flag reaches target only after THIS block's tid0 add, which is
// after THIS block's leading __syncthreads (drains vmcnt/lgkmcnt) -> every
// wave here is past its step-s LDS reads and its h-store is globally issued
// & drained. Staging chunks are wave-disjoint; S1 orders stage->MFMA.
__device__ __forceinline__ void rg_bar_fast(unsigned* ctr, unsigned target, int tid) {
  __syncthreads();
  if (tid == 0)
    __hip_atomic_fetch_add(ctr, 1u, __ATOMIC_RELAXED, __HIP_MEMORY_SCOPE_AGENT);
  while (__hip_atomic_load(ctr, __ATOMIC_RELAXED, __HIP_MEMORY_SCOPE_AGENT) < target)
    __builtin_amdgcn_s_sleep(8);
}

#define MFMA16(a,b,c) __builtin_amdgcn_mfma_f32_16x16x32_f16((a),(b),(c),0,0,0)

// 256 blocks x 768 threads, 1 block/CU (proven cooperative shape).
__global__ __launch_bounds__(NTHR, 3) void conv_lstm(Params P) {
  cg::grid_group grid = cg::this_grid();
  const int bid = blockIdx.x, tid = threadIdx.x;

  extern __shared__ __align__(16) f16 smem[];   // H0|H1|H2 (48 KB each) | stash

  f16*      WT   = (f16*)(P.ws);
  f16*      Hb   = (f16*)(P.ws + H_OFF);
  unsigned* bar  = (unsigned*)(P.ws + BAR_OFF); // [rg*16] 16 rg-ctrs, [256] grid ctr
  unsigned* gctr = bar + 256;

  // ---- init: weight swizzle into MFMA B-fragment order + zero h + zero ctrs ----
  {
    const int gt = bid * NTHR + tid;
    for (int slot = gt; slot < 786432; slot += NBLK * NTHR) {
      int lane = slot & 63, kkg = (slot >> 6) & 31, g16 = (slot >> 11) & 127, l = slot >> 18;
      int k = kkg * 32 + (lane >> 4) * 8;
      int p = g16 * 16 + (lane & 15);             // permuted gate-col: p = 4u+g
      int n = (p & 3) * 512 + (p >> 2);           // original col: g*512+u
      const float* s = P.lW + ((size_t)l * 1024 + k) * 2048 + n;
      f16x8 v;
      #pragma unroll
      for (int j = 0; j < 8; j++) v[j] = (f16)s[(size_t)j * 2048];
      *(f16x8*)(WT + (size_t)slot * 8) = v;
    }
    uint4 z4; z4.x = z4.y = z4.z = z4.w = 0u;
    uint4* zp = (uint4*)(P.ws + H_OFF);
    for (int i = gt; i < 294912; i += NBLK * NTHR) zp[i] = z4;
    if (bid == 0 && tid < 512) bar[tid] = 0u;
  }
  grid.sync();   // the ONE fence-ful sync: publishes WT / h-zeros / ctr-zeros

  // ---- thread geometry: 16 rowgroups x 16 colgroups ----
  const int sb   = tid >> 8;                      // layer sub-group (256 thr = 4 waves)
  const int tid2 = tid & 255;
  const int w2   = tid2 >> 6;                     // wave-in-subgroup: 32-pcol slice
  const int wv   = tid >> 6;                      // global wave id [0,12)
  const int L    = tid & 63;
  const int r16  = L & 15, quad = L >> 4;
  const int s4   = L & 3, r16q = r16 >> 2;
  const int rg   = bid >> 4, cgi = bid & 15;
  const int row0 = rg * 48;
  unsigned* rgc  = bar + rg * 16;

  const int ug = cgi * 32 + w2 * 8 + r16q;        // unit base for this lane
  float bia[2][4];
  #pragma unroll
  for (int ct2 = 0; ct2 < 2; ++ct2)
    #pragma unroll
    for (int g = 0; g < 4; ++g)
      bia[ct2][g] = P.lB[sb * 2048 + g * 512 + ug + ct2 * 4];
  float c6[6] = {0.f, 0.f, 0.f, 0.f, 0.f, 0.f};   // persistent c-state (VGPR)

  const size_t lstride = 768 * 512;
  const f16x8* Bb = (const f16x8*)WT
      + ((size_t)(sb * 128 + cgi * 8 + w2 * 2) * 32) * 64 + L;
  // stash in DEDICATED LDS (R2): [48][40] f16 per subgroup. Wave (sb,w2) owns
  // cols w2*8..w2*8+7 -> each row-chunk is exactly one 16B store.
  f16* stash = smem + STASH_F16 + sb * 1920;

  // ---- wavefront: 3 layers in parallel; h-tiles staged ONCE into shared LDS ----
  for (int s = 0; s < TSTEPS + 2; ++s) {
    const int t = s - sb;
    const bool act = (t >= 0 && t < TSTEPS);
    f16* hdo = Hb + (size_t)(sb * 2 + (t & 1)) * lstride;

    // shared h-tile sources (slot arithmetic: (x)&1 is well-defined for x<0)
    const f16* hs0 = Hb + (size_t)(0 * 2 + ((s - 1) & 1)) * lstride;  // h_l0[s-1]
    const f16* hs1 = Hb + (size_t)(1 * 2 + ((s - 2) & 1)) * lstride;  // h_l1[s-2]
    const f16* hs2 = Hb + (size_t)(2 * 2 + ((s - 3) & 1)) * lstride;  // h_l2[s-3]

    // ---- stage: all 12 waves fill H0|H1|H2 (48 frag-blocks of 1 KB each) ----
    // R4: swizzled source -> lanes 0..15 read 256 B contiguous per (kk,quad).
    // (entering here, the previous step's rg-barrier guarantees LDS is free)
    #pragma unroll
    for (int i = 0; i < 12; ++i) {
      int fb = wv * 12 + i;                       // [0,144)
      int buf = fb / 48, inner = fb - buf * 48;
      int kk = inner / 3, rt = inner - kk * 3;
      const f16* src = (buf == 0) ? hs0 : ((buf == 1) ? hs1 : hs2);
      int m = row0 + rt * 16 + r16;
      int cg8 = kk * 4 + quad;
      u32x4 v = *(volatile const u32x4*)(src + ((size_t)cg8 * 768 + m) * 8);
      *(u32x4*)(smem + buf * 24576 + inner * 512 + L * 8) = v;
    }
    __syncthreads();                              // S1: stage -> MFMA reads

    f32x4 acc[3][2];
    #pragma unroll
    for (int a = 0; a < 3; a++)
      #pragma unroll
      for (int b = 0; b < 2; b++) acc[a][b] = (f32x4){0.f, 0.f, 0.f, 0.f};

    if (act) {
      // token/emb base pointers for layer 0 (per-lane row)
      const float *e0, *e1, *e2;
      if (sb == 0) {
        int m0 = row0 + r16, m1 = m0 + 16, m2 = m0 + 32;
        int b0 = m0 & 255, tx0 = m0 >> 8;
        int b1 = m1 & 255, tx1 = m1 >> 8;
        int b2 = m2 & 255, tx2 = m2 >> 8;
        const int* tp0 = (tx0 == 0) ? P.t1 : ((tx0 == 1) ? P.t2 : P.t3);
        const int* tp1 = (tx1 == 0) ? P.t1 : ((tx1 == 1) ? P.t2 : P.t3);
        const int* tp2 = (tx2 == 0) ? P.t1 : ((tx2 == 1) ? P.t2 : P.t3);
        e0 = P.emb + (size_t)tp0[b0 * TSTEPS + t] * 512;
        e1 = P.emb + (size_t)tp1[b1 * TSTEPS + t] * 512;
        e2 = P.emb + (size_t)tp2[b2 * TSTEPS + t] * 512;
      }
      const f16* xbuf = smem + (sb - 1) * 24576;  // valid for sb>0
      const f16* hbuf = smem + sb * 24576;

      // x-side: k in [0,512)
      #pragma unroll 4
      for (int kk = 0; kk < 16; ++kk) {
        f16x8 a0, a1, a2;
        if (sb == 0) {
          int k = kk * 32 + quad * 8;
          a0 = emb_frag(e0 + k); a1 = emb_frag(e1 + k); a2 = emb_frag(e2 + k);
        } else {
          a0 = *(const f16x8*)(xbuf + (kk * 3 + 0) * 512 + L * 8);
          a1 = *(const f16x8*)(xbuf + (kk * 3 + 1) * 512 + L * 8);
          a2 = *(const f16x8*)(xbuf + (kk * 3 + 2) * 512 + L * 8);
        }
        f16x8 b0 = Bb[kk * 64], b1 = Bb[kk * 64 + 2048];
        acc[0][0] = MFMA16(a0, b0, acc[0][0]);
        acc[1][0] = MFMA16(a1, b0, acc[1][0]);
        acc[2][0] = MFMA16(a2, b0, acc[2][0]);
        acc[0][1] = MFMA16(a0, b1, acc[0][1]);
        acc[1][1] = MFMA16(a1, b1, acc[1][1]);
        acc[2][1] = MFMA16(a2, b1, acc[2][1]);
      }
      // h-side: k in [512,1024)
      #pragma unroll 4
      for (int kk = 16; kk < 32; ++kk) {
        int in3 = (kk - 16) * 3;
        f16x8 a0 = *(const f16x8*)(hbuf + (in3 + 0) * 512 + L * 8);
        f16x8 a1 = *(const f16x8*)(hbuf + (in3 + 1) * 512 + L * 8);
        f16x8 a2 = *(const f16x8*)(hbuf + (in3 + 2) * 512 + L * 8);
        f16x8 b0 = Bb[kk * 64], b1 = Bb[kk * 64 + 2048];
        acc[0][0] = MFMA16(a0, b0, acc[0][0]);
        acc[1][0] = MFMA16(a1, b0, acc[1][0]);
        acc[2][0] = MFMA16(a2, b0, acc[2][0]);
        acc[0][1] = MFMA16(a0, b1, acc[0][1]);
        acc[1][1] = MFMA16(a1, b1, acc[1][1]);
        acc[2][1] = MFMA16(a2, b1, acc[2][1]);
      }
    }
    // R2: no MFMA->elem sync (S2 removed; stash is dedicated LDS).

    // ---- elementwise: 4x4 lane<->reg transpose -> c/h; h out WAVE-LOCALLY ----
    // R3: S3 removed (wave-local handoff, lgkmcnt(0) only).
    // R4: store goes to the swizzled h layout -> lanes 0..47 write one 768 B
    // contiguous burst (fixes the R3 16B-partial-line write amplification).
    if (act) {
      #pragma unroll
      for (int rt = 0; rt < 3; ++rt) {
        #pragma unroll
        for (int ct2 = 0; ct2 < 2; ++ct2) {
          float x0 = acc[rt][ct2][0], x1 = acc[rt][ct2][1];
          float x2 = acc[rt][ct2][2], x3 = acc[rt][ct2][3];
          float a, b;
          a = (s4 & 1) ? x0 : x1;  b = (s4 & 1) ? x2 : x3;
          a = __shfl_xor(a, 1, 64); b = __shfl_xor(b, 1, 64);
          if (s4 & 1) { x0 = a; x2 = b; } else { x1 = a; x3 = b; }
          a = (s4 & 2) ? x0 : x2;  b = (s4 & 2) ? x1 : x3;
          a = __shfl_xor(a, 2, 64); b = __shfl_xor(b, 2, 64);
          if (s4 & 2) { x0 = a; x1 = b; } else { x2 = a; x3 = b; }
          float vi = x0 + bia[ct2][0], vj = x1 + bia[ct2][1];
          float vf = x2 + bia[ct2][2], vo = x3 + bia[ct2][3];
          int j = rt * 2 + ct2;
          float cn = sigmf(vf) * c6[j] + sigmf(vi) * tanhf_(vj);
          c6[j] = cn;
          int rl = rt * 16 + quad * 4 + s4;       // [0,48)
          int cl = w2 * 8 + ct2 * 4 + r16q;       // [0,32)
          stash[rl * 40 + cl] = (f16)(sigmf(vo) * tanhf_(cn));
        }
      }
      asm volatile("s_waitcnt lgkmcnt(0)" ::: "memory");  // wave-local LDS RAW fence
      if (L < 48) {                               // own 48x8-col block: 768 B burst
        u32x4 v = *(const u32x4*)(stash + L * 40 + w2 * 8);
        *(volatile u32x4*)(hdo + ((size_t)(cgi * 4 + w2) * 768 + row0 + L) * 8) = v;
      }
    }
    rg_bar_fast(rgc, 16u * (unsigned)(s + 1), tid);  // R7: no trailing sync
  }

  // ---------------- epilogue: relaxed grid barriers + volatile buffers ----------------
  float* scale1 = (float*)(P.ws + S1_OFF); float* off1 = (float*)(P.ws + O1_OFF);
  float* y1    = (float*)(P.ws + Y1_OFF);
  float* scale2 = (float*)(P.ws + S2_OFF); float* off2 = (float*)(P.ws + O2_OFF);
  float* y2    = (float*)(P.ws + Y2_OFF);
  float* scale3 = (float*)(P.ws + S3_OFF); float* off3 = (float*)(P.ws + O3_OFF);
  const f16* h2f = Hb + (size_t)(2 * 2 + 1) * lstride;   // top layer, t=127 (slot 1)

  bar_arrive_wait(gctr, 256u, tid);               // all rgs done -> h2f complete

  const int wvg = bid * 12 + wv;
  const int Le  = tid & 63;
  const float SC = 1.0507009873554805f, AL = 1.6732632423543772f;

  // E1: BN1 -> fused scale/offset for 1536 cols (one wave per col)
  // R4: swizzled h2f read -> 64 lanes span 1 KB contiguous (was 64 lines).
  if (wvg < 1536) {
    int c = wvg, tx = c >> 9, u = c & 511;
    const f16* base = h2f + (size_t)(u >> 3) * 6144 + (size_t)tx * 2048 + (u & 7);
    float sm = 0.f, s2 = 0.f;
    for (int r = Le; r < 256; r += 64) {
      float v = vldh(base + (size_t)r * 8);
      sm += v; s2 += v * v;
    }
    sm = wsum(sm); s2 = wsum(s2);
    if (Le == 0) {
      float mu = sm * (1.f / 256.f);
      float var = s2 * (1.f / 256.f) - mu * mu;
      float sc = rsqrtf(var + 1e-3f) * P.g1[c];
      vstf(scale1 + c, sc); vstf(off1 + c, P.be1[c] - mu * sc);
    }
  }
  bar_arrive_wait(gctr, 512u, tid);

  // E2: y1 = selu(rep_n @ W1 + b1): block = 16-row slab x 64-col slice, slab in LDS
  {
    const int rb16 = (bid >> 4) * 16, cb = bid & 15;
    f16*   slab = smem;                           // [16][1536] f16 (49,152 B)
    float* scl  = (float*)(smem + 24576);         // [1536]
    float* ofl  = scl + 1536;                     // [1536]
    for (int e = tid; e < 3072; e += NTHR) {      // 16-B chunks of the slab
      int r = e / 192, seg = e % 192;
      int u8 = seg * 8, tx = u8 >> 9, u = u8 & 511;
      u32x4 v = *(volatile const u32x4*)(h2f + ((size_t)(u >> 3) * 768 + tx * 256 + rb16 + r) * 8);
      *(u32x4*)(slab + r * 1536 + seg * 8) = v;
    }
    for (int k2 = tid; k2 < 1536; k2 += NTHR) { scl[k2] = vldf(scale1 + k2); ofl[k2] = vldf(off1 + k2); }
    __syncthreads();
    int rgrp = tid >> 6;
    if (rgrp < 8) {
      int c = cb * 64 + (tid & 63);
      int r0 = rgrp * 2, r1 = r0 + 1;
      float a0 = 0.f, a1 = 0.f;
      for (int k = 0; k < 1536; ++k) {
        float w = P.W1[(size_t)k * 1024 + c];
        float sck = scl[k], ofk = ofl[k];
        a0 += ((float)slab[r0 * 1536 + k] * sck + ofk) * w;
        a1 += ((float)slab[r1 * 1536 + k] * sck + ofk) * w;
      }
      float x0 = a0 + P.b1[c], x1 = a1 + P.b1[c];
      vstf(y1 + (size_t)(rb16 + r0) * 1024 + c, SC * (x0 > 0.f ? x0 : AL * expm1f(x0)));
      vstf(y1 + (size_t)(rb16 + r1) * 1024 + c, SC * (x1 > 0.f ? x1 : AL * expm1f(x1)));
    }
  }
  bar_arrive_wait(gctr, 768u, tid);

  // E3: BN2 scale/offset for 1024 cols (one wave per col)
  if (wvg < 1024) {
    int c = wvg;
    float sm = 0.f, s2 = 0.f;
    for (int r = Le; r < 256; r += 64) {
      float v = vldf(y1 + (size_t)r * 1024 + c);
      sm += v; s2 += v * v;
    }
    sm = wsum(sm); s2 = wsum(s2);
    if (Le == 0) {
      float mu = sm * (1.f / 256.f);
      float var = s2 * (1.f / 256.f) - mu * mu;
      float sc = rsqrtf(var + 1e-3f) * P.g2[c];
      vstf(scale2 + c, sc); vstf(off2 + c, P.be2[c] - mu * sc);
    }
  }
  bar_arrive_wait(gctr, 1024u, tid);

  // E4: y2 = selu(y1n @ W2 + b2): one wave per batch row. (R1 rewrite, kept:
  // scale2/off2 staged to LDS once; y1 row staged via 4 wide volatile loads;
  // dot runs on LDS broadcasts instead of 3 serial volatile loads per k.)
  {
    float* sc2  = (float*)smem;                   // [1024]
    float* of2  = sc2 + 1024;                     // [1024]
    float* rowb = of2 + 1024;                     // [12][1024]
    for (int k = tid; k < 1024; k += NTHR) { sc2[k] = vldf(scale2 + k); of2[k] = vldf(off2 + k); }
    __syncthreads();
    if (wvg < 256) {
      const float* yr = y1 + (size_t)wvg * 1024;
      u32x4 r0 = *(volatile const u32x4*)(yr + Le * 16);
      u32x4 r1 = *(volatile const u32x4*)(yr + Le * 16 + 4);
      u32x4 r2 = *(volatile const u32x4*)(yr + Le * 16 + 8);
      u32x4 r3 = *(volatile const u32x4*)(yr + Le * 16 + 12);
      float* rw = rowb + wv * 1024 + Le * 16;
      *(u32x4*)(rw) = r0; *(u32x4*)(rw + 4) = r1;
      *(u32x4*)(rw + 8) = r2; *(u32x4*)(rw + 12) = r3;
      asm volatile("s_waitcnt lgkmcnt(0)" ::: "memory");  // wave-local LDS RAW fence
      const float* rb = rowb + wv * 1024;
      int c0 = Le, c1 = Le + 64;
      float a0 = 0.f, a1 = 0.f;
      #pragma unroll 4
      for (int k = 0; k < 1024; ++k) {
        float v = rb[k] * sc2[k] + of2[k];
        a0 += v * P.W2[(size_t)k * 102 + c0];
        if (c1 < 102) a1 += v * P.W2[(size_t)k * 102 + c1];
      }
      {
        float x = a0 + P.b2[c0];
        vstf(y2 + (size_t)wvg * 102 + c0, SC * (x > 0.f ? x : AL * expm1f(x)));
      }
      if (c1 < 102) {
        float x = a1 + P.b2[c1];
        vstf(y2 + (size_t)wvg * 102 + c1, SC * (x > 0.f ? x : AL * expm1f(x)));
      }
    }
  }
  bar_arrive_wait(gctr, 1280u, tid);

  // E5: BN3 scale/offset for 102 cols (one wave per col)
  if (wvg < 102) {
    int c = wvg;
    float sm = 0.f, s2 = 0.f;
    for (int r = Le; r < 256; r += 64) {
      float v = vldf(y2 + (size_t)r * 102 + c);
      sm += v; s2 += v * v;
    }
    sm = wsum(sm); s2 = wsum(s2);
    if (Le == 0) {
      float mu = sm * (1.f / 256.f);
      float var = s2 * (1.f / 256.f) - mu * mu;
      float sc = rsqrtf(var + 1e-3f) * P.g3[c];
      vstf(scale3 + c, sc); vstf(off3 + c, P.be3[c] - mu * sc);
    }
  }
  bar_arrive_wait(gctr, 1536u, tid);

  // E6: out = y2n @ W3 + b3: one wave per batch row
  if (wvg < 256) {
    int row = wvg;
    int c = Le & 3, kq = Le >> 2;
    float part = 0.f;
    for (int k = kq; k < 102; k += 16) {
      float v = vldf(y2 + (size_t)row * 102 + k) * vldf(scale3 + k) + vldf(off3 + k);
      part += v * P.W3[k * 4 + c];
    }
    #pragma unroll
    for (int m = 4; m < 64; m <<= 1) part += __shfl_xor(part, m, 64);
    if (Le < 4) P.out[row * 4 + Le] = part + P.b3[Le];
  }
}

extern "C" void kernel_launch(void* const* d_in, const int* in_sizes, int n_in,
                              void* d_out, int out_size, void* d_ws, size_t ws_size,
                              hipStream_t stream) {
  if (ws_size < (size_t)WS_NEED) return;
  (void)hipFuncSetAttribute((const void*)conv_lstm,
                            hipFuncAttributeMaxDynamicSharedMemorySize, LDS_BYTES);
  Params prm;
  prm.t1  = (const int*)d_in[0];
  prm.t2  = (const int*)d_in[1];
  prm.t3  = (const int*)d_in[2];
  prm.emb = (const float*)d_in[3];
  prm.lW  = (const float*)d_in[4];
  prm.lB  = (const float*)d_in[5];
  prm.g1  = (const float*)d_in[6];  prm.be1 = (const float*)d_in[7];
  prm.W1  = (const float*)d_in[8];  prm.b1  = (const float*)d_in[9];
  prm.g2  = (const float*)d_in[10]; prm.be2 = (const float*)d_in[11];
  prm.W2  = (const float*)d_in[12]; prm.b2  = (const float*)d_in[13];
  prm.g3  = (const float*)d_in[14]; prm.be3 = (const float*)d_in[15];
  prm.W3  = (const float*)d_in[16]; prm.b3  = (const float*)d_in[17];
  prm.out = (float*)d_out;
  prm.ws  = (unsigned char*)d_ws;
  void* args[] = { &prm };
  hipLaunchCooperativeKernel((void*)conv_lstm, dim3(NBLK), dim3(NTHR), args,
                             LDS_BYTES, stream);
}

// Round 8
// 4596.634 us; speedup vs baseline: 1.4104x; 1.0180x over previous
//
#include <hip/hip_runtime.h>
#include <hip/hip_cooperative_groups.h>

namespace cg = cooperative_groups;

typedef _Float16 f16;
typedef f16 f16x8 __attribute__((ext_vector_type(8)));
typedef float f32x4 __attribute__((ext_vector_type(4)));
typedef unsigned int u32x4 __attribute__((ext_vector_type(4)));

#define TSTEPS 128
#define NBLK 256
#define NTHR 768
// 3 shared h-tile buffers x 48 KB + dedicated stash 3 x 3840 B = 158,976 B
#define LDS_BYTES 158976
#define STASH_F16 73728            // f16 offset of stash region (= 147456 B)

// ---------------- workspace layout (bytes) ----------------
#define WT_BYTES (3ull*128*32*64*16)            // swizzled f16 weights: 12,582,912
#define H_OFF    (WT_BYTES)
#define H_BYTES  (3ull*2*768*512*2)             // h double buffers (f16): 4,718,592
#define S1_OFF   (H_OFF + H_BYTES)
#define O1_OFF   (S1_OFF + 1536*4)
#define Y1_OFF   (O1_OFF + 1536*4)
#define S2_OFF   (Y1_OFF + 256ull*1024*4)
#define O2_OFF   (S2_OFF + 1024*4)
#define Y2_OFF   (O2_OFF + 1024*4)
#define S3_OFF   (Y2_OFF + 256ull*102*4)
#define O3_OFF   (S3_OFF + 128*4)
#define BAR_OFF  (O3_OFF + 128*4)               // gctr etc (zeroed in init)
#define FLAGS_OFF (BAR_OFF + 2048)              // R8: per-block step flags,
#define WS_NEED  (FLAGS_OFF + 16384)            //     u32 strided 64 B apart

// R4: h buffers are WAVE-MAJOR swizzled: h[buf][cg8][m][c8], cg8=col/8 in
// [0,64), m in [0,768), c8 in [0,8). One wave's per-step output (48 rows x
// one cg8) is 768 B CONTIGUOUS -> coalesced store without any block barrier.
// R7: weight-hoist (R5/R6) REVERTED -- allocator spills it to scratch.
// R8: per-rg barrier = 16 per-block flag STORES (64B apart, parallel) +
//     one-load-per-wave poll of all 16, replacing the contended RMW counter
//     whose 16 serialized far-atomic adds sat on the release critical path.

struct Params {
  const int *t1, *t2, *t3;
  const float *emb, *lW, *lB;
  const float *g1, *be1, *W1, *b1;
  const float *g2, *be2, *W2, *b2;
  const float *g3, *be3, *W3, *b3;
  float* out;
  unsigned char* ws;
};

__device__ __forceinline__ float sigmf(float x) {
  x = fminf(fmaxf(x, -30.f), 30.f);
  return 1.f / (1.f + __expf(-x));
}
__device__ __forceinline__ float tanhf_(float x) {
  x = fminf(fmaxf(x, -15.f), 15.f);
  float e = __expf(-2.f * x);
  return (1.f - e) / (1.f + e);
}
__device__ __forceinline__ float wsum(float v) {
  #pragma unroll
  for (int m = 1; m < 64; m <<= 1) v += __shfl_xor(v, m, 64);
  return v;
}
__device__ __forceinline__ float vldh(const f16* p) {
  unsigned short u = *(volatile const unsigned short*)p;
  union { unsigned short s; f16 h; } cv; cv.s = u;
  return (float)cv.h;
}
__device__ __forceinline__ float vldf(const float* p) { return *(volatile const float*)p; }
__device__ __forceinline__ void  vstf(float* p, float v) { *(volatile float*)p = v; }
__device__ __forceinline__ f16x8 emb_frag(const float* e) {
  float4 fa = *(const float4*)e, fb = *(const float4*)(e + 4);
  f16x8 v;
  v[0]=(f16)fa.x; v[1]=(f16)fa.y; v[2]=(f16)fa.z; v[3]=(f16)fa.w;
  v[4]=(f16)fb.x; v[5]=(f16)fb.y; v[6]=(f16)fb.z; v[7]=(f16)fb.w;
  return v;
}

// Conservative flag barrier (epilogue only): leading+trailing __syncthreads.
__device__ __forceinline__ void bar_arrive_wait(unsigned* ctr, unsigned target, int tid) {
  __syncthreads();
  if (tid == 0)
    __hip_atomic_fetch_add(ctr, 1u, __ATOMIC_RELAXED, __HIP_MEMORY_SCOPE_AGENT);
  if (tid < 64) {
    while (__hip_atomic_load(ctr, __ATOMIC_RELAXED, __HIP_MEMORY_SCOPE_AGENT) < target)
      __builtin_amdgcn_s_sleep(8);
  }
  __syncthreads();
}

#define MFMA16(a,b,c) __builtin_amdgcn_mfma_f32_16x16x32_f16((a),(b),(c),0,0,0)

// 256 blocks x 768 threads, 1 block/CU (proven cooperative shape).
__global__ __launch_bounds__(NTHR, 3) void conv_lstm(Params P) {
  cg::grid_group grid = cg::this_grid();
  const int bid = blockIdx.x, tid = threadIdx.x;

  extern __shared__ __align__(16) f16 smem[];   // H0|H1|H2 (48 KB each) | stash

  f16*      WT   = (f16*)(P.ws);
  f16*      Hb   = (f16*)(P.ws + H_OFF);
  unsigned* bar  = (unsigned*)(P.ws + BAR_OFF); // [256] grid ctr at +256
  unsigned* gctr = bar + 256;
  unsigned* flags = (unsigned*)(P.ws + FLAGS_OFF); // [bid*16], 64 B apart

  // ---- init: weight swizzle into MFMA B-fragment order + zero h + zero ctrs ----
  {
    const int gt = bid * NTHR + tid;
    for (int slot = gt; slot < 786432; slot += NBLK * NTHR) {
      int lane = slot & 63, kkg = (slot >> 6) & 31, g16 = (slot >> 11) & 127, l = slot >> 18;
      int k = kkg * 32 + (lane >> 4) * 8;
      int p = g16 * 16 + (lane & 15);             // permuted gate-col: p = 4u+g
      int n = (p & 3) * 512 + (p >> 2);           // original col: g*512+u
      const float* s = P.lW + ((size_t)l * 1024 + k) * 2048 + n;
      f16x8 v;
      #pragma unroll
      for (int j = 0; j < 8; j++) v[j] = (f16)s[(size_t)j * 2048];
      *(f16x8*)(WT + (size_t)slot * 8) = v;
    }
    uint4 z4; z4.x = z4.y = z4.z = z4.w = 0u;
    uint4* zp = (uint4*)(P.ws + H_OFF);
    for (int i = gt; i < 294912; i += NBLK * NTHR) zp[i] = z4;
    for (int i = gt; i < 4096; i += NBLK * NTHR) flags[i] = 0u;   // R8: flag zero
    if (bid == 0 && tid < 512) bar[tid] = 0u;
  }
  grid.sync();   // the ONE fence-ful sync: publishes WT / h-zeros / ctr-zeros

  // ---- thread geometry: 16 rowgroups x 16 colgroups ----
  const int sb   = tid >> 8;                      // layer sub-group (256 thr = 4 waves)
  const int tid2 = tid & 255;
  const int w2   = tid2 >> 6;                     // wave-in-subgroup: 32-pcol slice
  const int wv   = tid >> 6;                      // global wave id [0,12)
  const int L    = tid & 63;
  const int r16  = L & 15, quad = L >> 4;
  const int s4   = L & 3, r16q = r16 >> 2;
  const int rg   = bid >> 4, cgi = bid & 15;
  const int row0 = rg * 48;

  const int ug = cgi * 32 + w2 * 8 + r16q;        // unit base for this lane
  float bia[2][4];
  #pragma unroll
  for (int ct2 = 0; ct2 < 2; ++ct2)
    #pragma unroll
    for (int g = 0; g < 4; ++g)
      bia[ct2][g] = P.lB[sb * 2048 + g * 512 + ug + ct2 * 4];
  float c6[6] = {0.f, 0.f, 0.f, 0.f, 0.f, 0.f};   // persistent c-state (VGPR)

  const size_t lstride = 768 * 512;
  const f16x8* Bb = (const f16x8*)WT
      + ((size_t)(sb * 128 + cgi * 8 + w2 * 2) * 32) * 64 + L;
  // stash in DEDICATED LDS (R2): [48][40] f16 per subgroup. Wave (sb,w2) owns
  // cols w2*8..w2*8+7 -> each row-chunk is exactly one 16B store.
  f16* stash = smem + STASH_F16 + sb * 1920;

  // R8 poll address: lane L reads the flag of block (rg, L&15).
  unsigned* myflag  = flags + bid * 16;
  unsigned* pollptr = flags + rg * 256 + (L & 15) * 16;

  // ---- wavefront: 3 layers in parallel; h-tiles staged ONCE into shared LDS ----
  for (int s = 0; s < TSTEPS + 2; ++s) {
    const int t = s - sb;
    const bool act = (t >= 0 && t < TSTEPS);
    f16* hdo = Hb + (size_t)(sb * 2 + (t & 1)) * lstride;

    // shared h-tile sources (slot arithmetic: (x)&1 is well-defined for x<0)
    const f16* hs0 = Hb + (size_t)(0 * 2 + ((s - 1) & 1)) * lstride;  // h_l0[s-1]
    const f16* hs1 = Hb + (size_t)(1 * 2 + ((s - 2) & 1)) * lstride;  // h_l1[s-2]
    const f16* hs2 = Hb + (size_t)(2 * 2 + ((s - 3) & 1)) * lstride;  // h_l2[s-3]

    // ---- stage: all 12 waves fill H0|H1|H2 (48 frag-blocks of 1 KB each) ----
    // R4: swizzled source -> lanes 0..15 read 256 B contiguous per (kk,quad).
    // (entering here, the step-(s-1) flag-wait guarantees LDS is free)
    #pragma unroll
    for (int i = 0; i < 12; ++i) {
      int fb = wv * 12 + i;                       // [0,144)
      int buf = fb / 48, inner = fb - buf * 48;
      int kk = inner / 3, rt = inner - kk * 3;
      const f16* src = (buf == 0) ? hs0 : ((buf == 1) ? hs1 : hs2);
      int m = row0 + rt * 16 + r16;
      int cg8 = kk * 4 + quad;
      u32x4 v = *(volatile const u32x4*)(src + ((size_t)cg8 * 768 + m) * 8);
      *(u32x4*)(smem + buf * 24576 + inner * 512 + L * 8) = v;
    }
    __syncthreads();                              // S1: stage -> MFMA reads

    f32x4 acc[3][2];
    #pragma unroll
    for (int a = 0; a < 3; a++)
      #pragma unroll
      for (int b = 0; b < 2; b++) acc[a][b] = (f32x4){0.f, 0.f, 0.f, 0.f};

    if (act) {
      // token/emb base pointers for layer 0 (per-lane row)
      const float *e0, *e1, *e2;
      if (sb == 0) {
        int m0 = row0 + r16, m1 = m0 + 16, m2 = m0 + 32;
        int b0 = m0 & 255, tx0 = m0 >> 8;
        int b1 = m1 & 255, tx1 = m1 >> 8;
        int b2 = m2 & 255, tx2 = m2 >> 8;
        const int* tp0 = (tx0 == 0) ? P.t1 : ((tx0 == 1) ? P.t2 : P.t3);
        const int* tp1 = (tx1 == 0) ? P.t1 : ((tx1 == 1) ? P.t2 : P.t3);
        const int* tp2 = (tx2 == 0) ? P.t1 : ((tx2 == 1) ? P.t2 : P.t3);
        e0 = P.emb + (size_t)tp0[b0 * TSTEPS + t] * 512;
        e1 = P.emb + (size_t)tp1[b1 * TSTEPS + t] * 512;
        e2 = P.emb + (size_t)tp2[b2 * TSTEPS + t] * 512;
      }
      const f16* xbuf = smem + (sb - 1) * 24576;  // valid for sb>0
      const f16* hbuf = smem + sb * 24576;

      // x-side: k in [0,512)
      #pragma unroll 4
      for (int kk = 0; kk < 16; ++kk) {
        f16x8 a0, a1, a2;
        if (sb == 0) {
          int k = kk * 32 + quad * 8;
          a0 = emb_frag(e0 + k); a1 = emb_frag(e1 + k); a2 = emb_frag(e2 + k);
        } else {
          a0 = *(const f16x8*)(xbuf + (kk * 3 + 0) * 512 + L * 8);
          a1 = *(const f16x8*)(xbuf + (kk * 3 + 1) * 512 + L * 8);
          a2 = *(const f16x8*)(xbuf + (kk * 3 + 2) * 512 + L * 8);
        }
        f16x8 b0 = Bb[kk * 64], b1 = Bb[kk * 64 + 2048];
        acc[0][0] = MFMA16(a0, b0, acc[0][0]);
        acc[1][0] = MFMA16(a1, b0, acc[1][0]);
        acc[2][0] = MFMA16(a2, b0, acc[2][0]);
        acc[0][1] = MFMA16(a0, b1, acc[0][1]);
        acc[1][1] = MFMA16(a1, b1, acc[1][1]);
        acc[2][1] = MFMA16(a2, b1, acc[2][1]);
      }
      // h-side: k in [512,1024)
      #pragma unroll 4
      for (int kk = 16; kk < 32; ++kk) {
        int in3 = (kk - 16) * 3;
        f16x8 a0 = *(const f16x8*)(hbuf + (in3 + 0) * 512 + L * 8);
        f16x8 a1 = *(const f16x8*)(hbuf + (in3 + 1) * 512 + L * 8);
        f16x8 a2 = *(const f16x8*)(hbuf + (in3 + 2) * 512 + L * 8);
        f16x8 b0 = Bb[kk * 64], b1 = Bb[kk * 64 + 2048];
        acc[0][0] = MFMA16(a0, b0, acc[0][0]);
        acc[1][0] = MFMA16(a1, b0, acc[1][0]);
        acc[2][0] = MFMA16(a2, b0, acc[2][0]);
        acc[0][1] = MFMA16(a0, b1, acc[0][1]);
        acc[1][1] = MFMA16(a1, b1, acc[1][1]);
        acc[2][1] = MFMA16(a2, b1, acc[2][1]);
      }
    }
    // R2: no MFMA->elem sync (S2 removed; stash is dedicated LDS).

    // ---- elementwise: 4x4 lane<->reg transpose -> c/h; h out WAVE-LOCALLY ----
    // R3: S3 removed (wave-local handoff, lgkmcnt(0) only).
    // R4: store goes to the swizzled h layout -> lanes 0..47 write one 768 B
    // contiguous burst.
    if (act) {
      #pragma unroll
      for (int rt = 0; rt < 3; ++rt) {
        #pragma unroll
        for (int ct2 = 0; ct2 < 2; ++ct2) {
          float x0 = acc[rt][ct2][0], x1 = acc[rt][ct2][1];
          float x2 = acc[rt][ct2][2], x3 = acc[rt][ct2][3];
          float a, b;
          a = (s4 & 1) ? x0 : x1;  b = (s4 & 1) ? x2 : x3;
          a = __shfl_xor(a, 1, 64); b = __shfl_xor(b, 1, 64);
          if (s4 & 1) { x0 = a; x2 = b; } else { x1 = a; x3 = b; }
          a = (s4 & 2) ? x0 : x2;  b = (s4 & 2) ? x1 : x3;
          a = __shfl_xor(a, 2, 64); b = __shfl_xor(b, 2, 64);
          if (s4 & 2) { x0 = a; x1 = b; } else { x2 = a; x3 = b; }
          float vi = x0 + bia[ct2][0], vj = x1 + bia[ct2][1];
          float vf = x2 + bia[ct2][2], vo = x3 + bia[ct2][3];
          int j = rt * 2 + ct2;
          float cn = sigmf(vf) * c6[j] + sigmf(vi) * tanhf_(vj);
          c6[j] = cn;
          int rl = rt * 16 + quad * 4 + s4;       // [0,48)
          int cl = w2 * 8 + ct2 * 4 + r16q;       // [0,32)
          stash[rl * 40 + cl] = (f16)(sigmf(vo) * tanhf_(cn));
        }
      }
      asm volatile("s_waitcnt lgkmcnt(0)" ::: "memory");  // wave-local LDS RAW fence
      if (L < 48) {                               // own 48x8-col block: 768 B burst
        u32x4 v = *(const u32x4*)(stash + L * 40 + w2 * 8);
        *(volatile u32x4*)(hdo + ((size_t)(cgi * 4 + w2) * 768 + row0 + L) * 8) = v;
      }
    }

    // ---- R8 rg-barrier: parallel per-block flag stores + one-load poll ----
    // Leading __syncthreads drains all waves' h-stores (vmcnt 0). tid0 then
    // PUBLISHES this block's step with a plain relaxed store (no RMW, flags
    // 64 B apart -> all 16 publishes land in parallel). Each wave polls all
    // 16 rg flags with a single load (lane L reads flag L&15) and releases
    // on __all(>=tgt). Own flag is in the poll set -> same safety as R7.
    __syncthreads();
    if (tid == 0)
      __hip_atomic_store(myflag, (unsigned)(s + 1), __ATOMIC_RELAXED,
                         __HIP_MEMORY_SCOPE_AGENT);
    {
      unsigned tgt = (unsigned)(s + 1);
      for (;;) {
        unsigned v = __hip_atomic_load(pollptr, __ATOMIC_RELAXED,
                                       __HIP_MEMORY_SCOPE_AGENT);
        if (__all(v >= tgt)) break;
        __builtin_amdgcn_s_sleep(8);
      }
    }
  }

  // ---------------- epilogue: relaxed grid barriers + volatile buffers ----------------
  float* scale1 = (float*)(P.ws + S1_OFF); float* off1 = (float*)(P.ws + O1_OFF);
  float* y1    = (float*)(P.ws + Y1_OFF);
  float* scale2 = (float*)(P.ws + S2_OFF); float* off2 = (float*)(P.ws + O2_OFF);
  float* y2    = (float*)(P.ws + Y2_OFF);
  float* scale3 = (float*)(P.ws + S3_OFF); float* off3 = (float*)(P.ws + O3_OFF);
  const f16* h2f = Hb + (size_t)(2 * 2 + 1) * lstride;   // top layer, t=127 (slot 1)

  bar_arrive_wait(gctr, 256u, tid);               // all rgs done -> h2f complete

  const int wvg = bid * 12 + wv;
  const int Le  = tid & 63;
  const float SC = 1.0507009873554805f, AL = 1.6732632423543772f;

  // E1: BN1 -> fused scale/offset for 1536 cols (one wave per col)
  // R4: swizzled h2f read -> 64 lanes span 1 KB contiguous (was 64 lines).
  if (wvg < 1536) {
    int c = wvg, tx = c >> 9, u = c & 511;
    const f16* base = h2f + (size_t)(u >> 3) * 6144 + (size_t)tx * 2048 + (u & 7);
    float sm = 0.f, s2 = 0.f;
    for (int r = Le; r < 256; r += 64) {
      float v = vldh(base + (size_t)r * 8);
      sm += v; s2 += v * v;
    }
    sm = wsum(sm); s2 = wsum(s2);
    if (Le == 0) {
      float mu = sm * (1.f / 256.f);
      float var = s2 * (1.f / 256.f) - mu * mu;
      float sc = rsqrtf(var + 1e-3f) * P.g1[c];
      vstf(scale1 + c, sc); vstf(off1 + c, P.be1[c] - mu * sc);
    }
  }
  bar_arrive_wait(gctr, 512u, tid);

  // E2: y1 = selu(rep_n @ W1 + b1): block = 16-row slab x 64-col slice, slab in LDS
  {
    const int rb16 = (bid >> 4) * 16, cb = bid & 15;
    f16*   slab = smem;                           // [16][1536] f16 (49,152 B)
    float* scl  = (float*)(smem + 24576);         // [1536]
    float* ofl  = scl + 1536;                     // [1536]
    for (int e = tid; e < 3072; e += NTHR) {      // 16-B chunks of the slab
      int r = e / 192, seg = e % 192;
      int u8 = seg * 8, tx = u8 >> 9, u = u8 & 511;
      u32x4 v = *(volatile const u32x4*)(h2f + ((size_t)(u >> 3) * 768 + tx * 256 + rb16 + r) * 8);
      *(u32x4*)(slab + r * 1536 + seg * 8) = v;
    }
    for (int k2 = tid; k2 < 1536; k2 += NTHR) { scl[k2] = vldf(scale1 + k2); ofl[k2] = vldf(off1 + k2); }
    __syncthreads();
    int rgrp = tid >> 6;
    if (rgrp < 8) {
      int c = cb * 64 + (tid & 63);
      int r0 = rgrp * 2, r1 = r0 + 1;
      float a0 = 0.f, a1 = 0.f;
      for (int k = 0; k < 1536; ++k) {
        float w = P.W1[(size_t)k * 1024 + c];
        float sck = scl[k], ofk = ofl[k];
        a0 += ((float)slab[r0 * 1536 + k] * sck + ofk) * w;
        a1 += ((float)slab[r1 * 1536 + k] * sck + ofk) * w;
      }
      float x0 = a0 + P.b1[c], x1 = a1 + P.b1[c];
      vstf(y1 + (size_t)(rb16 + r0) * 1024 + c, SC * (x0 > 0.f ? x0 : AL * expm1f(x0)));
      vstf(y1 + (size_t)(rb16 + r1) * 1024 + c, SC * (x1 > 0.f ? x1 : AL * expm1f(x1)));
    }
  }
  bar_arrive_wait(gctr, 768u, tid);

  // E3: BN2 scale/offset for 1024 cols (one wave per col)
  if (wvg < 1024) {
    int c = wvg;
    float sm = 0.f, s2 = 0.f;
    for (int r = Le; r < 256; r += 64) {
      float v = vldf(y1 + (size_t)r * 1024 + c);
      sm += v; s2 += v * v;
    }
    sm = wsum(sm); s2 = wsum(s2);
    if (Le == 0) {
      float mu = sm * (1.f / 256.f);
      float var = s2 * (1.f / 256.f) - mu * mu;
      float sc = rsqrtf(var + 1e-3f) * P.g2[c];
      vstf(scale2 + c, sc); vstf(off2 + c, P.be2[c] - mu * sc);
    }
  }
  bar_arrive_wait(gctr, 1024u, tid);

  // E4: y2 = selu(y1n @ W2 + b2): one wave per batch row. (R1 rewrite, kept:
  // scale2/off2 staged to LDS once; y1 row staged via 4 wide volatile loads;
  // dot runs on LDS broadcasts instead of 3 serial volatile loads per k.)
  {
    float* sc2  = (float*)smem;                   // [1024]
    float* of2  = sc2 + 1024;                     // [1024]
    float* rowb = of2 + 1024;                     // [12][1024]
    for (int k = tid; k < 1024; k += NTHR) { sc2[k] = vldf(scale2 + k); of2[k] = vldf(off2 + k); }
    __syncthreads();
    if (wvg < 256) {
      const float* yr = y1 + (size_t)wvg * 1024;
      u32x4 r0 = *(volatile const u32x4*)(yr + Le * 16);
      u32x4 r1 = *(volatile const u32x4*)(yr + Le * 16 + 4);
      u32x4 r2 = *(volatile const u32x4*)(yr + Le * 16 + 8);
      u32x4 r3 = *(volatile const u32x4*)(yr + Le * 16 + 12);
      float* rw = rowb + wv * 1024 + Le * 16;
      *(u32x4*)(rw) = r0; *(u32x4*)(rw + 4) = r1;
      *(u32x4*)(rw + 8) = r2; *(u32x4*)(rw + 12) = r3;
      asm volatile("s_waitcnt lgkmcnt(0)" ::: "memory");  // wave-local LDS RAW fence
      const float* rb = rowb + wv * 1024;
      int c0 = Le, c1 = Le + 64;
      float a0 = 0.f, a1 = 0.f;
      #pragma unroll 4
      for (int k = 0; k < 1024; ++k) {
        float v = rb[k] * sc2[k] + of2[k];
        a0 += v * P.W2[(size_t)k * 102 + c0];
        if (c1 < 102) a1 += v * P.W2[(size_t)k * 102 + c1];
      }
      {
        float x = a0 + P.b2[c0];
        vstf(y2 + (size_t)wvg * 102 + c0, SC * (x > 0.f ? x : AL * expm1f(x)));
      }
      if (c1 < 102) {
        float x = a1 + P.b2[c1];
        vstf(y2 + (size_t)wvg * 102 + c1, SC * (x > 0.f ? x : AL * expm1f(x)));
      }
    }
  }
  bar_arrive_wait(gctr, 1280u, tid);

  // E5: BN3 scale/offset for 102 cols (one wave per col)
  if (wvg < 102) {
    int c = wvg;
    float sm = 0.f, s2 = 0.f;
    for (int r = Le; r < 256; r += 64) {
      float v = vldf(y2 + (size_t)r * 102 + c);
      sm += v; s2 += v * v;
    }
    sm = wsum(sm); s2 = wsum(s2);
    if (Le == 0) {
      float mu = sm * (1.f / 256.f);
      float var = s2 * (1.f / 256.f) - mu * mu;
      float sc = rsqrtf(var + 1e-3f) * P.g3[c];
      vstf(scale3 + c, sc); vstf(off3 + c, P.be3[c] - mu * sc);
    }
  }
  bar_arrive_wait(gctr, 1536u, tid);

  // E6: out = y2n @ W3 + b3: one wave per batch row
  if (wvg < 256) {
    int row = wvg;
    int c = Le & 3, kq = Le >> 2;
    float part = 0.f;
    for (int k = kq; k < 102; k += 16) {
      float v = vldf(y2 + (size_t)row * 102 + k) * vldf(scale3 + k) + vldf(off3 + k);
      part += v * P.W3[k * 4 + c];
    }
    #pragma unroll
    for (int m = 4; m < 64; m <<= 1) part += __shfl_xor(part, m, 64);
    if (Le < 4) P.out[row * 4 + Le] = part + P.b3[Le];
  }
}

extern "C" void kernel_launch(void* const* d_in, const int* in_sizes, int n_in,
                              void* d_out, int out_size, void* d_ws, size_t ws_size,
                              hipStream_t stream) {
  if (ws_size < (size_t)WS_NEED) return;
  (void)hipFuncSetAttribute((const void*)conv_lstm,
                            hipFuncAttributeMaxDynamicSharedMemorySize, LDS_BYTES);
  Params prm;
  prm.t1  = (const int*)d_in[0];
  prm.t2  = (const int*)d_in[1];
  prm.t3  = (const int*)d_in[2];
  prm.emb = (const float*)d_in[3];
  prm.lW  = (const float*)d_in[4];
  prm.lB  = (const float*)d_in[5];
  prm.g1  = (const float*)d_in[6];  prm.be1 = (const float*)d_in[7];
  prm.W1  = (const float*)d_in[8];  prm.b1  = (const float*)d_in[9];
  prm.g2  = (const float*)d_in[10]; prm.be2 = (const float*)d_in[11];
  prm.W2  = (const float*)d_in[12]; prm.b2  = (const float*)d_in[13];
  prm.g3  = (const float*)d_in[14]; prm.be3 = (const float*)d_in[15];
  prm.W3  = (const float*)d_in[16]; prm.b3  = (const float*)d_in[17];
  prm.out = (float*)d_out;
  prm.ws  = (unsigned char*)d_ws;
  void* args[] = { &prm };
  hipLaunchCooperativeKernel((void*)conv_lstm, dim3(NBLK), dim3(NTHR), args,
                             LDS_BYTES, stream);
}

// Round 9
// 4583.507 us; speedup vs baseline: 1.4145x; 1.0029x over previous
//
#include <hip/hip_runtime.h>
#include <hip/hip_cooperative_groups.h>

namespace cg = cooperative_groups;

typedef _Float16 f16;
typedef f16 f16x8 __attribute__((ext_vector_type(8)));
typedef float f32x4 __attribute__((ext_vector_type(4)));
typedef unsigned int u32x4 __attribute__((ext_vector_type(4)));

#define TSTEPS 128
#define NBLK 256
#define NTHR 768
// 3 shared h-tile buffers x 48 KB + dedicated stash 3 x 3840 B = 158,976 B
#define LDS_BYTES 158976
#define STASH_F16 73728            // f16 offset of stash region (= 147456 B)

// ---------------- workspace layout (bytes) ----------------
#define WT_BYTES (3ull*128*32*64*16)            // swizzled f16 weights: 12,582,912
#define H_OFF    (WT_BYTES)
#define H_BYTES  (3ull*2*768*512*2)             // h double buffers (f16): 4,718,592
#define S1_OFF   (H_OFF + H_BYTES)
#define O1_OFF   (S1_OFF + 1536*4)
#define Y1_OFF   (O1_OFF + 1536*4)
#define S2_OFF   (Y1_OFF + 256ull*1024*4)
#define O2_OFF   (S2_OFF + 1024*4)
#define Y2_OFF   (O2_OFF + 1024*4)
#define S3_OFF   (Y2_OFF + 256ull*102*4)
#define O3_OFF   (S3_OFF + 128*4)
#define BAR_OFF  (O3_OFF + 128*4)               // gctr etc (zeroed in init)
#define FLAGS_OFF (BAR_OFF + 2048)              // R8: per-block step flags,
#define WS_NEED  (FLAGS_OFF + 16384)            //     u32 strided 64 B apart

// R4: h buffers are WAVE-MAJOR swizzled: h[buf][cg8][m][c8]; one wave's
// per-step output is a 768 B contiguous burst (no block barrier needed).
// R7: weight-hoist REVERTED (allocator spills to scratch; two-round proof).
// R8: per-rg barrier = 16 per-block flag STORES + one-load-per-wave poll.
// R9: CLOCK DISCRIMINATOR -- hot-loop poll s_sleep(8) replaced by a dependent
//     VALU spin. Theory: all waves sleeping at the per-step barrier parks the
//     DVFS clock at ~0.7 GHz effective (MfmaUtil*dur invariant ~515 us across
//     all rounds implies ~25k cy per 35 us step). Active spin raises apparent
//     utilization over the governor window -> clocks rise -> all phases
//     shrink. Read: MfmaUtil*dur < 450 us = confirmed; ~515 us = theory dead.

struct Params {
  const int *t1, *t2, *t3;
  const float *emb, *lW, *lB;
  const float *g1, *be1, *W1, *b1;
  const float *g2, *be2, *W2, *b2;
  const float *g3, *be3, *W3, *b3;
  float* out;
  unsigned char* ws;
};

__device__ __forceinline__ float sigmf(float x) {
  x = fminf(fmaxf(x, -30.f), 30.f);
  return 1.f / (1.f + __expf(-x));
}
__device__ __forceinline__ float tanhf_(float x) {
  x = fminf(fmaxf(x, -15.f), 15.f);
  float e = __expf(-2.f * x);
  return (1.f - e) / (1.f + e);
}
__device__ __forceinline__ float wsum(float v) {
  #pragma unroll
  for (int m = 1; m < 64; m <<= 1) v += __shfl_xor(v, m, 64);
  return v;
}
__device__ __forceinline__ float vldh(const f16* p) {
  unsigned short u = *(volatile const unsigned short*)p;
  union { unsigned short s; f16 h; } cv; cv.s = u;
  return (float)cv.h;
}
__device__ __forceinline__ float vldf(const float* p) { return *(volatile const float*)p; }
__device__ __forceinline__ void  vstf(float* p, float v) { *(volatile float*)p = v; }
__device__ __forceinline__ f16x8 emb_frag(const float* e) {
  float4 fa = *(const float4*)e, fb = *(const float4*)(e + 4);
  f16x8 v;
  v[0]=(f16)fa.x; v[1]=(f16)fa.y; v[2]=(f16)fa.z; v[3]=(f16)fa.w;
  v[4]=(f16)fb.x; v[5]=(f16)fb.y; v[6]=(f16)fb.z; v[7]=(f16)fb.w;
  return v;
}

// Conservative flag barrier (epilogue only): leading+trailing __syncthreads.
__device__ __forceinline__ void bar_arrive_wait(unsigned* ctr, unsigned target, int tid) {
  __syncthreads();
  if (tid == 0)
    __hip_atomic_fetch_add(ctr, 1u, __ATOMIC_RELAXED, __HIP_MEMORY_SCOPE_AGENT);
  if (tid < 64) {
    while (__hip_atomic_load(ctr, __ATOMIC_RELAXED, __HIP_MEMORY_SCOPE_AGENT) < target)
      __builtin_amdgcn_s_sleep(8);
  }
  __syncthreads();
}

#define MFMA16(a,b,c) __builtin_amdgcn_mfma_f32_16x16x32_f16((a),(b),(c),0,0,0)

// 256 blocks x 768 threads, 1 block/CU (proven cooperative shape).
__global__ __launch_bounds__(NTHR, 3) void conv_lstm(Params P) {
  cg::grid_group grid = cg::this_grid();
  const int bid = blockIdx.x, tid = threadIdx.x;

  extern __shared__ __align__(16) f16 smem[];   // H0|H1|H2 (48 KB each) | stash

  f16*      WT   = (f16*)(P.ws);
  f16*      Hb   = (f16*)(P.ws + H_OFF);
  unsigned* bar  = (unsigned*)(P.ws + BAR_OFF); // [256] grid ctr at +256
  unsigned* gctr = bar + 256;
  unsigned* flags = (unsigned*)(P.ws + FLAGS_OFF); // [bid*16], 64 B apart

  // ---- init: weight swizzle into MFMA B-fragment order + zero h + zero ctrs ----
  {
    const int gt = bid * NTHR + tid;
    for (int slot = gt; slot < 786432; slot += NBLK * NTHR) {
      int lane = slot & 63, kkg = (slot >> 6) & 31, g16 = (slot >> 11) & 127, l = slot >> 18;
      int k = kkg * 32 + (lane >> 4) * 8;
      int p = g16 * 16 + (lane & 15);             // permuted gate-col: p = 4u+g
      int n = (p & 3) * 512 + (p >> 2);           // original col: g*512+u
      const float* s = P.lW + ((size_t)l * 1024 + k) * 2048 + n;
      f16x8 v;
      #pragma unroll
      for (int j = 0; j < 8; j++) v[j] = (f16)s[(size_t)j * 2048];
      *(f16x8*)(WT + (size_t)slot * 8) = v;
    }
    uint4 z4; z4.x = z4.y = z4.z = z4.w = 0u;
    uint4* zp = (uint4*)(P.ws + H_OFF);
    for (int i = gt; i < 294912; i += NBLK * NTHR) zp[i] = z4;
    for (int i = gt; i < 4096; i += NBLK * NTHR) flags[i] = 0u;   // flag zero
    if (bid == 0 && tid < 512) bar[tid] = 0u;
  }
  grid.sync();   // the ONE fence-ful sync: publishes WT / h-zeros / ctr-zeros

  // ---- thread geometry: 16 rowgroups x 16 colgroups ----
  const int sb   = tid >> 8;                      // layer sub-group (256 thr = 4 waves)
  const int tid2 = tid & 255;
  const int w2   = tid2 >> 6;                     // wave-in-subgroup: 32-pcol slice
  const int wv   = tid >> 6;                      // global wave id [0,12)
  const int L    = tid & 63;
  const int r16  = L & 15, quad = L >> 4;
  const int s4   = L & 3, r16q = r16 >> 2;
  const int rg   = bid >> 4, cgi = bid & 15;
  const int row0 = rg * 48;

  const int ug = cgi * 32 + w2 * 8 + r16q;        // unit base for this lane
  float bia[2][4];
  #pragma unroll
  for (int ct2 = 0; ct2 < 2; ++ct2)
    #pragma unroll
    for (int g = 0; g < 4; ++g)
      bia[ct2][g] = P.lB[sb * 2048 + g * 512 + ug + ct2 * 4];
  float c6[6] = {0.f, 0.f, 0.f, 0.f, 0.f, 0.f};   // persistent c-state (VGPR)

  const size_t lstride = 768 * 512;
  const f16x8* Bb = (const f16x8*)WT
      + ((size_t)(sb * 128 + cgi * 8 + w2 * 2) * 32) * 64 + L;
  // stash in DEDICATED LDS (R2): [48][40] f16 per subgroup. Wave (sb,w2) owns
  // cols w2*8..w2*8+7 -> each row-chunk is exactly one 16B store.
  f16* stash = smem + STASH_F16 + sb * 1920;

  // R8 poll address: lane L reads the flag of block (rg, L&15).
  unsigned* myflag  = flags + bid * 16;
  unsigned* pollptr = flags + rg * 256 + (L & 15) * 16;

  // ---- wavefront: 3 layers in parallel; h-tiles staged ONCE into shared LDS ----
  for (int s = 0; s < TSTEPS + 2; ++s) {
    const int t = s - sb;
    const bool act = (t >= 0 && t < TSTEPS);
    f16* hdo = Hb + (size_t)(sb * 2 + (t & 1)) * lstride;

    // shared h-tile sources (slot arithmetic: (x)&1 is well-defined for x<0)
    const f16* hs0 = Hb + (size_t)(0 * 2 + ((s - 1) & 1)) * lstride;  // h_l0[s-1]
    const f16* hs1 = Hb + (size_t)(1 * 2 + ((s - 2) & 1)) * lstride;  // h_l1[s-2]
    const f16* hs2 = Hb + (size_t)(2 * 2 + ((s - 3) & 1)) * lstride;  // h_l2[s-3]

    // ---- stage: all 12 waves fill H0|H1|H2 (48 frag-blocks of 1 KB each) ----
    // R4: swizzled source -> lanes 0..15 read 256 B contiguous per (kk,quad).
    // (entering here, the step-(s-1) flag-wait guarantees LDS is free)
    #pragma unroll
    for (int i = 0; i < 12; ++i) {
      int fb = wv * 12 + i;                       // [0,144)
      int buf = fb / 48, inner = fb - buf * 48;
      int kk = inner / 3, rt = inner - kk * 3;
      const f16* src = (buf == 0) ? hs0 : ((buf == 1) ? hs1 : hs2);
      int m = row0 + rt * 16 + r16;
      int cg8 = kk * 4 + quad;
      u32x4 v = *(volatile const u32x4*)(src + ((size_t)cg8 * 768 + m) * 8);
      *(u32x4*)(smem + buf * 24576 + inner * 512 + L * 8) = v;
    }
    __syncthreads();                              // S1: stage -> MFMA reads

    f32x4 acc[3][2];
    #pragma unroll
    for (int a = 0; a < 3; a++)
      #pragma unroll
      for (int b = 0; b < 2; b++) acc[a][b] = (f32x4){0.f, 0.f, 0.f, 0.f};

    if (act) {
      // token/emb base pointers for layer 0 (per-lane row)
      const float *e0, *e1, *e2;
      if (sb == 0) {
        int m0 = row0 + r16, m1 = m0 + 16, m2 = m0 + 32;
        int b0 = m0 & 255, tx0 = m0 >> 8;
        int b1 = m1 & 255, tx1 = m1 >> 8;
        int b2 = m2 & 255, tx2 = m2 >> 8;
        const int* tp0 = (tx0 == 0) ? P.t1 : ((tx0 == 1) ? P.t2 : P.t3);
        const int* tp1 = (tx1 == 0) ? P.t1 : ((tx1 == 1) ? P.t2 : P.t3);
        const int* tp2 = (tx2 == 0) ? P.t1 : ((tx2 == 1) ? P.t2 : P.t3);
        e0 = P.emb + (size_t)tp0[b0 * TSTEPS + t] * 512;
        e1 = P.emb + (size_t)tp1[b1 * TSTEPS + t] * 512;
        e2 = P.emb + (size_t)tp2[b2 * TSTEPS + t] * 512;
      }
      const f16* xbuf = smem + (sb - 1) * 24576;  // valid for sb>0
      const f16* hbuf = smem + sb * 24576;

      // x-side: k in [0,512)
      #pragma unroll 4
      for (int kk = 0; kk < 16; ++kk) {
        f16x8 a0, a1, a2;
        if (sb == 0) {
          int k = kk * 32 + quad * 8;
          a0 = emb_frag(e0 + k); a1 = emb_frag(e1 + k); a2 = emb_frag(e2 + k);
        } else {
          a0 = *(const f16x8*)(xbuf + (kk * 3 + 0) * 512 + L * 8);
          a1 = *(const f16x8*)(xbuf + (kk * 3 + 1) * 512 + L * 8);
          a2 = *(const f16x8*)(xbuf + (kk * 3 + 2) * 512 + L * 8);
        }
        f16x8 b0 = Bb[kk * 64], b1 = Bb[kk * 64 + 2048];
        acc[0][0] = MFMA16(a0, b0, acc[0][0]);
        acc[1][0] = MFMA16(a1, b0, acc[1][0]);
        acc[2][0] = MFMA16(a2, b0, acc[2][0]);
        acc[0][1] = MFMA16(a0, b1, acc[0][1]);
        acc[1][1] = MFMA16(a1, b1, acc[1][1]);
        acc[2][1] = MFMA16(a2, b1, acc[2][1]);
      }
      // h-side: k in [512,1024)
      #pragma unroll 4
      for (int kk = 16; kk < 32; ++kk) {
        int in3 = (kk - 16) * 3;
        f16x8 a0 = *(const f16x8*)(hbuf + (in3 + 0) * 512 + L * 8);
        f16x8 a1 = *(const f16x8*)(hbuf + (in3 + 1) * 512 + L * 8);
        f16x8 a2 = *(const f16x8*)(hbuf + (in3 + 2) * 512 + L * 8);
        f16x8 b0 = Bb[kk * 64], b1 = Bb[kk * 64 + 2048];
        acc[0][0] = MFMA16(a0, b0, acc[0][0]);
        acc[1][0] = MFMA16(a1, b0, acc[1][0]);
        acc[2][0] = MFMA16(a2, b0, acc[2][0]);
        acc[0][1] = MFMA16(a0, b1, acc[0][1]);
        acc[1][1] = MFMA16(a1, b1, acc[1][1]);
        acc[2][1] = MFMA16(a2, b1, acc[2][1]);
      }
    }
    // R2: no MFMA->elem sync (S2 removed; stash is dedicated LDS).

    // ---- elementwise: 4x4 lane<->reg transpose -> c/h; h out WAVE-LOCALLY ----
    if (act) {
      #pragma unroll
      for (int rt = 0; rt < 3; ++rt) {
        #pragma unroll
        for (int ct2 = 0; ct2 < 2; ++ct2) {
          float x0 = acc[rt][ct2][0], x1 = acc[rt][ct2][1];
          float x2 = acc[rt][ct2][2], x3 = acc[rt][ct2][3];
          float a, b;
          a = (s4 & 1) ? x0 : x1;  b = (s4 & 1) ? x2 : x3;
          a = __shfl_xor(a, 1, 64); b = __shfl_xor(b, 1, 64);
          if (s4 & 1) { x0 = a; x2 = b; } else { x1 = a; x3 = b; }
          a = (s4 & 2) ? x0 : x2;  b = (s4 & 2) ? x1 : x3;
          a = __shfl_xor(a, 2, 64); b = __shfl_xor(b, 2, 64);
          if (s4 & 2) { x0 = a; x1 = b; } else { x2 = a; x3 = b; }
          float vi = x0 + bia[ct2][0], vj = x1 + bia[ct2][1];
          float vf = x2 + bia[ct2][2], vo = x3 + bia[ct2][3];
          int j = rt * 2 + ct2;
          float cn = sigmf(vf) * c6[j] + sigmf(vi) * tanhf_(vj);
          c6[j] = cn;
          int rl = rt * 16 + quad * 4 + s4;       // [0,48)
          int cl = w2 * 8 + ct2 * 4 + r16q;       // [0,32)
          stash[rl * 40 + cl] = (f16)(sigmf(vo) * tanhf_(cn));
        }
      }
      asm volatile("s_waitcnt lgkmcnt(0)" ::: "memory");  // wave-local LDS RAW fence
      if (L < 48) {                               // own 48x8-col block: 768 B burst
        u32x4 v = *(const u32x4*)(stash + L * 40 + w2 * 8);
        *(volatile u32x4*)(hdo + ((size_t)(cgi * 4 + w2) * 768 + row0 + L) * 8) = v;
      }
    }

    // ---- R8 rg-barrier (flag stores + poll), R9: ACTIVE-SPIN wait ----
    // s_sleep(8) -> dependent v_fmac chain (~200 cy) between polls. Keeps the
    // SIMDs visibly busy for the DVFS governor during the wait phases without
    // extra memory traffic; poll rate comparable to the old sleep granularity.
    __syncthreads();
    if (tid == 0)
      __hip_atomic_store(myflag, (unsigned)(s + 1), __ATOMIC_RELAXED,
                         __HIP_MEMORY_SCOPE_AGENT);
    {
      unsigned tgt = (unsigned)(s + 1);
      float junk = 1.0f + (float)(tid & 7) * 1e-6f;
      for (;;) {
        unsigned v = __hip_atomic_load(pollptr, __ATOMIC_RELAXED,
                                       __HIP_MEMORY_SCOPE_AGENT);
        if (__all(v >= tgt)) break;
        #pragma unroll
        for (int z = 0; z < 48; ++z)
          asm volatile("v_fmac_f32 %0, %1, %1" : "+v"(junk) : "v"(1.000001f));
      }
    }
  }

  // ---------------- epilogue: relaxed grid barriers + volatile buffers ----------------
  float* scale1 = (float*)(P.ws + S1_OFF); float* off1 = (float*)(P.ws + O1_OFF);
  float* y1    = (float*)(P.ws + Y1_OFF);
  float* scale2 = (float*)(P.ws + S2_OFF); float* off2 = (float*)(P.ws + O2_OFF);
  float* y2    = (float*)(P.ws + Y2_OFF);
  float* scale3 = (float*)(P.ws + S3_OFF); float* off3 = (float*)(P.ws + O3_OFF);
  const f16* h2f = Hb + (size_t)(2 * 2 + 1) * lstride;   // top layer, t=127 (slot 1)

  bar_arrive_wait(gctr, 256u, tid);               // all rgs done -> h2f complete

  const int wvg = bid * 12 + wv;
  const int Le  = tid & 63;
  const float SC = 1.0507009873554805f, AL = 1.6732632423543772f;

  // E1: BN1 -> fused scale/offset for 1536 cols (one wave per col)
  // R4: swizzled h2f read -> 64 lanes span 1 KB contiguous (was 64 lines).
  if (wvg < 1536) {
    int c = wvg, tx = c >> 9, u = c & 511;
    const f16* base = h2f + (size_t)(u >> 3) * 6144 + (size_t)tx * 2048 + (u & 7);
    float sm = 0.f, s2 = 0.f;
    for (int r = Le; r < 256; r += 64) {
      float v = vldh(base + (size_t)r * 8);
      sm += v; s2 += v * v;
    }
    sm = wsum(sm); s2 = wsum(s2);
    if (Le == 0) {
      float mu = sm * (1.f / 256.f);
      float var = s2 * (1.f / 256.f) - mu * mu;
      float sc = rsqrtf(var + 1e-3f) * P.g1[c];
      vstf(scale1 + c, sc); vstf(off1 + c, P.be1[c] - mu * sc);
    }
  }
  bar_arrive_wait(gctr, 512u, tid);

  // E2: y1 = selu(rep_n @ W1 + b1): block = 16-row slab x 64-col slice, slab in LDS
  {
    const int rb16 = (bid >> 4) * 16, cb = bid & 15;
    f16*   slab = smem;                           // [16][1536] f16 (49,152 B)
    float* scl  = (float*)(smem + 24576);         // [1536]
    float* ofl  = scl + 1536;                     // [1536]
    for (int e = tid; e < 3072; e += NTHR) {      // 16-B chunks of the slab
      int r = e / 192, seg = e % 192;
      int u8 = seg * 8, tx = u8 >> 9, u = u8 & 511;
      u32x4 v = *(volatile const u32x4*)(h2f + ((size_t)(u >> 3) * 768 + tx * 256 + rb16 + r) * 8);
      *(u32x4*)(slab + r * 1536 + seg * 8) = v;
    }
    for (int k2 = tid; k2 < 1536; k2 += NTHR) { scl[k2] = vldf(scale1 + k2); ofl[k2] = vldf(off1 + k2); }
    __syncthreads();
    int rgrp = tid >> 6;
    if (rgrp < 8) {
      int c = cb * 64 + (tid & 63);
      int r0 = rgrp * 2, r1 = r0 + 1;
      float a0 = 0.f, a1 = 0.f;
      for (int k = 0; k < 1536; ++k) {
        float w = P.W1[(size_t)k * 1024 + c];
        float sck = scl[k], ofk = ofl[k];
        a0 += ((float)slab[r0 * 1536 + k] * sck + ofk) * w;
        a1 += ((float)slab[r1 * 1536 + k] * sck + ofk) * w;
      }
      float x0 = a0 + P.b1[c], x1 = a1 + P.b1[c];
      vstf(y1 + (size_t)(rb16 + r0) * 1024 + c, SC * (x0 > 0.f ? x0 : AL * expm1f(x0)));
      vstf(y1 + (size_t)(rb16 + r1) * 1024 + c, SC * (x1 > 0.f ? x1 : AL * expm1f(x1)));
    }
  }
  bar_arrive_wait(gctr, 768u, tid);

  // E3: BN2 scale/offset for 1024 cols (one wave per col)
  if (wvg < 1024) {
    int c = wvg;
    float sm = 0.f, s2 = 0.f;
    for (int r = Le; r < 256; r += 64) {
      float v = vldf(y1 + (size_t)r * 1024 + c);
      sm += v; s2 += v * v;
    }
    sm = wsum(sm); s2 = wsum(s2);
    if (Le == 0) {
      float mu = sm * (1.f / 256.f);
      float var = s2 * (1.f / 256.f) - mu * mu;
      float sc = rsqrtf(var + 1e-3f) * P.g2[c];
      vstf(scale2 + c, sc); vstf(off2 + c, P.be2[c] - mu * sc);
    }
  }
  bar_arrive_wait(gctr, 1024u, tid);

  // E4: y2 = selu(y1n @ W2 + b2): one wave per batch row. (R1 rewrite, kept.)
  {
    float* sc2  = (float*)smem;                   // [1024]
    float* of2  = sc2 + 1024;                     // [1024]
    float* rowb = of2 + 1024;                     // [12][1024]
    for (int k = tid; k < 1024; k += NTHR) { sc2[k] = vldf(scale2 + k); of2[k] = vldf(off2 + k); }
    __syncthreads();
    if (wvg < 256) {
      const float* yr = y1 + (size_t)wvg * 1024;
      u32x4 r0 = *(volatile const u32x4*)(yr + Le * 16);
      u32x4 r1 = *(volatile const u32x4*)(yr + Le * 16 + 4);
      u32x4 r2 = *(volatile const u32x4*)(yr + Le * 16 + 8);
      u32x4 r3 = *(volatile const u32x4*)(yr + Le * 16 + 12);
      float* rw = rowb + wv * 1024 + Le * 16;
      *(u32x4*)(rw) = r0; *(u32x4*)(rw + 4) = r1;
      *(u32x4*)(rw + 8) = r2; *(u32x4*)(rw + 12) = r3;
      asm volatile("s_waitcnt lgkmcnt(0)" ::: "memory");  // wave-local LDS RAW fence
      const float* rb = rowb + wv * 1024;
      int c0 = Le, c1 = Le + 64;
      float a0 = 0.f, a1 = 0.f;
      #pragma unroll 4
      for (int k = 0; k < 1024; ++k) {
        float v = rb[k] * sc2[k] + of2[k];
        a0 += v * P.W2[(size_t)k * 102 + c0];
        if (c1 < 102) a1 += v * P.W2[(size_t)k * 102 + c1];
      }
      {
        float x = a0 + P.b2[c0];
        vstf(y2 + (size_t)wvg * 102 + c0, SC * (x > 0.f ? x : AL * expm1f(x)));
      }
      if (c1 < 102) {
        float x = a1 + P.b2[c1];
        vstf(y2 + (size_t)wvg * 102 + c1, SC * (x > 0.f ? x : AL * expm1f(x)));
      }
    }
  }
  bar_arrive_wait(gctr, 1280u, tid);

  // E5: BN3 scale/offset for 102 cols (one wave per col)
  if (wvg < 102) {
    int c = wvg;
    float sm = 0.f, s2 = 0.f;
    for (int r = Le; r < 256; r += 64) {
      float v = vldf(y2 + (size_t)r * 102 + c);
      sm += v; s2 += v * v;
    }
    sm = wsum(sm); s2 = wsum(s2);
    if (Le == 0) {
      float mu = sm * (1.f / 256.f);
      float var = s2 * (1.f / 256.f) - mu * mu;
      float sc = rsqrtf(var + 1e-3f) * P.g3[c];
      vstf(scale3 + c, sc); vstf(off3 + c, P.be3[c] - mu * sc);
    }
  }
  bar_arrive_wait(gctr, 1536u, tid);

  // E6: out = y2n @ W3 + b3: one wave per batch row
  if (wvg < 256) {
    int row = wvg;
    int c = Le & 3, kq = Le >> 2;
    float part = 0.f;
    for (int k = kq; k < 102; k += 16) {
      float v = vldf(y2 + (size_t)row * 102 + k) * vldf(scale3 + k) + vldf(off3 + k);
      part += v * P.W3[k * 4 + c];
    }
    #pragma unroll
    for (int m = 4; m < 64; m <<= 1) part += __shfl_xor(part, m, 64);
    if (Le < 4) P.out[row * 4 + Le] = part + P.b3[Le];
  }
}

extern "C" void kernel_launch(void* const* d_in, const int* in_sizes, int n_in,
                              void* d_out, int out_size, void* d_ws, size_t ws_size,
                              hipStream_t stream) {
  if (ws_size < (size_t)WS_NEED) return;
  (void)hipFuncSetAttribute((const void*)conv_lstm,
                            hipFuncAttributeMaxDynamicSharedMemorySize, LDS_BYTES);
  Params prm;
  prm.t1  = (const int*)d_in[0];
  prm.t2  = (const int*)d_in[1];
  prm.t3  = (const int*)d_in[2];
  prm.emb = (const float*)d_in[3];
  prm.lW  = (const float*)d_in[4];
  prm.lB  = (const float*)d_in[5];
  prm.g1  = (const float*)d_in[6];  prm.be1 = (const float*)d_in[7];
  prm.W1  = (const float*)d_in[8];  prm.b1  = (const float*)d_in[9];
  prm.g2  = (const float*)d_in[10]; prm.be2 = (const float*)d_in[11];
  prm.W2  = (const float*)d_in[12]; prm.b2  = (const float*)d_in[13];
  prm.g3  = (const float*)d_in[14]; prm.be3 = (const float*)d_in[15];
  prm.W3  = (const float*)d_in[16]; prm.b3  = (const float*)d_in[17];
  prm.out = (float*)d_out;
  prm.ws  = (unsigned char*)d_ws;
  void* args[] = { &prm };
  hipLaunchCooperativeKernel((void*)conv_lstm, dim3(NBLK), dim3(NTHR), args,
                             LDS_BYTES, stream);
}